// Round 2
// baseline (340.765 us; speedup 1.0000x reference)
//
#include <hip/hip_runtime.h>
#include <hip/hip_bf16.h>
#include <math.h>

// FLASH (GAU-style) fused block. Round 12: gemm_h256 K-loop restructured into
// the m201-style 2-phase-per-K-step schedule (16 MFMA + 4-8 ds_read + 2 gload
// + 2 barriers per phase; counted vmcnt(8) once per K-step, never 0 in the
// main loop). Slot ring, staging addresses, swizzle, epilogues unchanged —
// the new schedule is a strict ordering refinement of the R11 kernel.
// b=4, n=4096, dim=512, hid=1024, qk=128, group=256.

#define BATCH 4
#define SEQ   4096
#define TROWS 16384      // BATCH*SEQ
#define DIMD  512
#define HIDD  1024
#define QKD   128
#define GRP   256
#define NGRP  16         // SEQ/GRP
#define BGRP  64         // BATCH*NGRP
#define EPIW  132        // padded LDS epilogue row stride (f32 path, 128-tiles)
#define EPB   130        // bf16 full-tile epilogue row stride (shorts)

typedef unsigned short bfraw;
typedef __attribute__((ext_vector_type(8))) short bf16x8;
typedef __attribute__((ext_vector_type(8))) unsigned short u16x8;
typedef __attribute__((ext_vector_type(4))) unsigned int u32x4;
typedef __attribute__((ext_vector_type(4))) float f32x4;

__device__ __forceinline__ float bf2f(bfraw u) {
    union { float f; unsigned int i; } c;
    c.i = ((unsigned int)u) << 16;
    return c.f;
}
__device__ __forceinline__ bfraw f2bf(float f) {
    unsigned int x = __float_as_uint(f);
    unsigned int r = (x + 0x7fffu + ((x >> 16) & 1u)) >> 16;   // RNE
    return (bfraw)r;
}
__device__ __forceinline__ unsigned int pkbf(float lo, float hi) {
    __hip_bfloat162 h2 = __float22bfloat162_rn(make_float2(lo, hi));
    union { __hip_bfloat162 h; unsigned int u; } c; c.h = h2;
    return c.u;
}
// 16 contiguous f32 -> 16 bf16 at dst (two 16B stores), packed cvt.
__device__ __forceinline__ void store16bf(bfraw* dst, const float* src) {
    u32x4 a, b;
    #pragma unroll
    for (int k = 0; k < 4; ++k) a[k] = pkbf(src[2 * k], src[2 * k + 1]);
    #pragma unroll
    for (int k = 0; k < 4; ++k) b[k] = pkbf(src[8 + 2 * k], src[8 + 2 * k + 1]);
    *(u32x4*)dst = a;
    *(u32x4*)(dst + 8) = b;
}
__device__ __forceinline__ float silu_f(float z) {
    return z / (1.f + __expf(-z));
}
__device__ __forceinline__ void gload_lds16(const void* g, void* l) {
    __builtin_amdgcn_global_load_lds(
        (const __attribute__((address_space(1))) unsigned int*)g,
        (__attribute__((address_space(3))) unsigned int*)l, 16, 0, 0);
}

// ===================== legacy 128^2 engine (other kernels) =====================
// One BK=32 MFMA step on staged tiles (4 waves, each 64x64 = 4x4 frags).
__device__ __forceinline__ void mfma_step(const bfraw* As, const bfraw* Bs,
                                          f32x4 acc[4][4], int wm, int wn,
                                          int q, int mi) {
    bf16x8 af[4], bfg[4];
    #pragma unroll
    for (int i = 0; i < 4; ++i)
        af[i] = *(const bf16x8*)&As[(size_t)(wm * 64 + i * 16 + mi) * 32 + q * 8];
    #pragma unroll
    for (int j = 0; j < 4; ++j)
        bfg[j] = *(const bf16x8*)&Bs[(size_t)(wn * 64 + j * 16 + mi) * 32 + q * 8];
    #pragma unroll
    for (int i = 0; i < 4; ++i)
        #pragma unroll
        for (int j = 0; j < 4; ++j)
            acc[i][j] = __builtin_amdgcn_mfma_f32_16x16x32_bf16(af[i], bfg[j], acc[i][j], 0, 0, 0);
}

// Double-buffered pipelined K-loop. 33280 bytes: 2x(A 8KB + B 8KB) + epi overlay.
#define SMEMP_DECL                                              \
    __shared__ __align__(16) char smem_[33280];                 \
    bfraw* A0buf = (bfraw*)smem_;                               \
    bfraw* B0buf = (bfraw*)(smem_ + 8192);                      \
    bfraw* A1buf = (bfraw*)(smem_ + 16384);                     \
    bfraw* B1buf = (bfraw*)(smem_ + 24576);

#define PIPE_DSTS                                               \
    bfraw* a0d  = A0buf + wid * 512;                            \
    bfraw* a0d2 = A0buf + 2048 + wid * 512;                     \
    bfraw* b0d  = B0buf + wid * 512;                            \
    bfraw* b0d2 = B0buf + 2048 + wid * 512;                     \
    bfraw* a1d  = A1buf + wid * 512;                            \
    bfraw* a1d2 = A1buf + 2048 + wid * 512;                     \
    bfraw* b1d  = B1buf + wid * 512;                            \
    bfraw* b1d2 = B1buf + 2048 + wid * 512;

#define KLOOP_PRE(Abase, Astr, Bbase, Bstr)                                    \
    const bfraw* pa0 = (Abase) + (size_t)(t >> 2) * (Astr) + (t & 3) * 8;      \
    const bfraw* pa1 = pa0 + (size_t)64 * (Astr);                              \
    const bfraw* pb0 = (Bbase) + (size_t)(t >> 2) * (Bstr) + (t & 3) * 8;      \
    const bfraw* pb1 = pb0 + (size_t)64 * (Bstr);

#define STAGE0                                                                 \
    do { gload_lds16(pa0, a0d); gload_lds16(pa1, a0d2);                        \
         gload_lds16(pb0, b0d); gload_lds16(pb1, b0d2);                        \
         pa0 += 32; pa1 += 32; pb0 += 32; pb1 += 32; } while (0)
#define STAGE1                                                                 \
    do { gload_lds16(pa0, a1d); gload_lds16(pa1, a1d2);                        \
         gload_lds16(pb0, b1d); gload_lds16(pb1, b1d2);                        \
         pa0 += 32; pa1 += 32; pb0 += 32; pb1 += 32; } while (0)

// NIT must be even (all call sites: K/32 ∈ {4,8,16,32}).
#define PIPE_LOOP(NIT, Abase, Astr, Bbase, Bstr)                               \
    {                                                                          \
        KLOOP_PRE(Abase, Astr, Bbase, Bstr)                                    \
        STAGE0;                                                                \
        for (int it = 0; it < (NIT); it += 2) {                                \
            __syncthreads();                                                   \
            if (it + 1 < (NIT)) STAGE1;                                        \
            mfma_step(A0buf, B0buf, acc, wm, wn, q, mi);                       \
            __syncthreads();                                                   \
            if (it + 2 < (NIT)) STAGE0;                                        \
            if (it + 1 < (NIT))                                                \
                mfma_step(A1buf, B1buf, acc, wm, wn, q, mi);                   \
        }                                                                      \
        __syncthreads();                                                       \
    }

__device__ __forceinline__ int epi_row(int p, int lr) {
    return (lr < 16) ? (p * 16 + lr) : (64 + p * 16 + (lr - 16));
}

// ------------- prep: ln (blocks 0..4095) + 3 weight transposes -------------
__global__ __launch_bounds__(256) void prep_kernel(const float* __restrict__ x,
                                                   const float* __restrict__ lnw,
                                                   const float* __restrict__ lnb,
                                                   const float* __restrict__ Wh,
                                                   const float* __restrict__ Wo,
                                                   const float* __restrict__ Wqk,
                                                   bfraw* __restrict__ normb,
                                                   bfraw* __restrict__ WhT,
                                                   bfraw* __restrict__ WoT,
                                                   bfraw* __restrict__ WqkT) {
    __shared__ float tile[32][33];
    int bid = blockIdx.x;
    int t = threadIdx.x;
    if (bid < 4096) {
        int row  = bid * 4 + (t >> 6);
        int lane = t & 63;
        const float* xr = x + (size_t)row * DIMD;
        float4 v0 = ((const float4*)xr)[lane];
        float4 v1 = ((const float4*)xr)[lane + 64];
        float s  = v0.x + v0.y + v0.z + v0.w + v1.x + v1.y + v1.z + v1.w;
        float ss = v0.x*v0.x + v0.y*v0.y + v0.z*v0.z + v0.w*v0.w
                 + v1.x*v1.x + v1.y*v1.y + v1.z*v1.z + v1.w*v1.w;
        #pragma unroll
        for (int off = 32; off; off >>= 1) {
            s  += __shfl_xor(s, off);
            ss += __shfl_xor(ss, off);
        }
        float mu  = s * (1.f / DIMD);
        float var = ss * (1.f / DIMD) - mu * mu;
        float inv = rsqrtf(var + 1e-5f);
        float4 w0 = ((const float4*)lnw)[lane],  w1 = ((const float4*)lnw)[lane + 64];
        float4 b0 = ((const float4*)lnb)[lane],  b1 = ((const float4*)lnb)[lane + 64];
        unsigned int o0 = pkbf((v0.x - mu) * inv * w0.x + b0.x,
                               (v0.y - mu) * inv * w0.y + b0.y);
        unsigned int o1 = pkbf((v0.z - mu) * inv * w0.z + b0.z,
                               (v0.w - mu) * inv * w0.w + b0.w);
        unsigned int o2 = pkbf((v1.x - mu) * inv * w1.x + b1.x,
                               (v1.y - mu) * inv * w1.y + b1.y);
        unsigned int o3 = pkbf((v1.z - mu) * inv * w1.z + b1.z,
                               (v1.w - mu) * inv * w1.w + b1.w);
        unsigned int* brow = (unsigned int*)(normb + (size_t)row * DIMD);
        ((uint2*)brow)[lane]      = make_uint2(o0, o1);
        ((uint2*)brow)[lane + 64] = make_uint2(o2, o3);
        return;
    }
    bid -= 4096;
    const float* in; bfraw* outp; int R, C, nx;
    if (bid < 1024)      { in = Wh;  outp = WhT;  R = DIMD; C = 2 * HIDD; nx = 64; }
    else if (bid < 1536) { bid -= 1024; in = Wo;  outp = WoT;  R = HIDD; C = DIMD; nx = 16; }
    else                 { bid -= 1536; in = Wqk; outp = WqkT; R = DIMD; C = QKD;  nx = 4; }
    int c0 = (bid % nx) * 32, r0 = (bid / nx) * 32;
    int tr = t >> 3, tc4 = (t & 7) * 4;
    float4 v = *(const float4*)&in[(size_t)(r0 + tr) * C + c0 + tc4];
    tile[tr][tc4 + 0] = v.x; tile[tr][tc4 + 1] = v.y;
    tile[tr][tc4 + 2] = v.z; tile[tr][tc4 + 3] = v.w;
    __syncthreads();
    ushort4 s;
    s.x = f2bf(tile[tc4 + 0][tr]);
    s.y = f2bf(tile[tc4 + 1][tr]);
    s.z = f2bf(tile[tc4 + 2][tr]);
    s.w = f2bf(tile[tc4 + 3][tr]);
    *(ushort4*)&outp[(size_t)(c0 + tr) * R + r0 + tc4] = s;
}

// ================= 256^2, 8-wave, 4-slot-ring h+qk GEMM (2-phase) =================
// Grid: 576 blocks (XCD-bijective swizzle -> (ct 0..8, by 0..63)), 512 thr.
// LDS: 4 slots x (A 16K + B 16K) = 128 KiB; epilogue overlays the same space.
// Per K-step j (slot j&3), two phases:
//  alpha: 8 ds_read (A mf0-3 + B nf0-3), stage A-half of tile j+3, barrier,
//         lgkmcnt(0), setprio(1), 16 MFMA, setprio(0), barrier.
//  beta:  4 ds_read (A mf4-7, B reused in-reg), stage B-half of tile j+3,
//         counted vmcnt(8), barrier, lgkmcnt(0), setprio(1), 16 MFMA,
//         setprio(0), barrier.
// Slot lifetimes identical to R11 (stage of slot s happens >=1 barrier after
// all reads of s completed); vmcnt(8) still guarantees tile j+1 landed before
// step j+1's first read.
__global__ __launch_bounds__(512, 2) void gemm_h256(
    const bfraw* __restrict__ A,      // normb [16384][512]
    const bfraw* __restrict__ WhT,    // [2048][512]
    const bfraw* __restrict__ WqkT,   // [128][512]
    const float* __restrict__ bh,     // [2048]
    const float* __restrict__ bqk,    // [128]
    const float* __restrict__ gamma,  // [4][128]
    const float* __restrict__ beta,   // [4][128]
    bfraw* __restrict__ vT,
    bfraw* __restrict__ gate,
    bfraw* __restrict__ qq,
    bfraw* __restrict__ lq,
    bfraw* __restrict__ kk,
    bfraw* __restrict__ lkT) {
    __shared__ __align__(16) char smem_[131072];
    const int t = threadIdx.x;
    const int lane = t & 63, wid = t >> 6;
    const int wm = wid >> 2, wn = wid & 3;
    const int q = lane >> 4, mi = lane & 15;
    // XCD-bijective swizzle: 576 = 72*8; same-by column tiles stay on one XCD.
    int nid = (blockIdx.x & 7) * 72 + (blockIdx.x >> 3);
    const int ct = nid % 9, by = nid / 9;
    const int r0 = by * 256, c0 = ct * 256;

    // ---- staging: pre-swizzled global sources, linear LDS dests ----
    // physical o = chunk*8192 + wid*1024 + lane*16; line=o>>7, pslot=(o>>4)&7,
    // lslot = pslot ^ (line&7); row = 2*line + (lslot>>2); k = (lslot&3)*8.
    const int lslot = (lane & 7) ^ (lane >> 3);
    const int rbase = wid * 16 + (lane >> 3) * 2 + (lslot >> 2);   // 0..127
    const int kel   = (lslot & 3) * 8;
    const bfraw* As0 = A + (size_t)(r0 + rbase) * DIMD + kel;
    const bfraw* As1 = As0 + (size_t)128 * DIMD;
    const bfraw* Bs0; const bfraw* Bs1;
    if (ct < 8) {
        Bs0 = WhT + (size_t)(c0 + rbase) * DIMD + kel;
        Bs1 = Bs0 + (size_t)128 * DIMD;
    } else {
        Bs0 = WqkT + (size_t)rbase * DIMD + kel;   // rows 0..127 real
        Bs1 = Bs0;                                 // rows 128..255 garbage dup
    }
    // ---- swizzled LDS read offsets (verified conflict-free) ----
    const int swz = ((((mi & 1) << 2) | q) ^ ((mi >> 1) & 7)) << 4;
    const int a_off = (wm * 64 + (mi >> 1)) * 128 + swz;
    const int b_off = (wn * 32 + (mi >> 1)) * 128 + swz;
    const int ldst = wid * 1024;

#define GH_STAGE(KT, SLOT)                                                    \
    do {                                                                      \
        char* sb_ = smem_ + (SLOT) * 32768;                                   \
        gload_lds16(As0 + (KT) * 32, sb_ + ldst);                             \
        gload_lds16(As1 + (KT) * 32, sb_ + 8192 + ldst);                      \
        gload_lds16(Bs0 + (KT) * 32, sb_ + 16384 + ldst);                     \
        gload_lds16(Bs1 + (KT) * 32, sb_ + 24576 + ldst);                     \
    } while (0)
#define GH_STAGE_A(KT, SLOT)                                                  \
    do {                                                                      \
        char* sb_ = smem_ + (SLOT) * 32768;                                   \
        gload_lds16(As0 + (KT) * 32, sb_ + ldst);                             \
        gload_lds16(As1 + (KT) * 32, sb_ + 8192 + ldst);                      \
    } while (0)
#define GH_STAGE_B(KT, SLOT)                                                  \
    do {                                                                      \
        char* sb_ = smem_ + (SLOT) * 32768;                                   \
        gload_lds16(Bs0 + (KT) * 32, sb_ + 16384 + ldst);                     \
        gload_lds16(Bs1 + (KT) * 32, sb_ + 24576 + ldst);                     \
    } while (0)

    f32x4 acc[8][4] = {};
    GH_STAGE(0, 0);
    GH_STAGE(1, 1);
    GH_STAGE(2, 2);
    asm volatile("s_waitcnt vmcnt(8)" ::: "memory");
    __builtin_amdgcn_s_barrier();

    #pragma unroll
    for (int j = 0; j < 16; ++j) {
        const char* cb = smem_ + (j & 3) * 32768;
        bf16x8 af0[4], af1[4], bfr[4];
        // ---- phase alpha: A mf0-3 + B, stage A-half of tile j+3 ----
        #pragma unroll
        for (int mf = 0; mf < 4; ++mf)
            af0[mf] = *(const bf16x8*)(cb + a_off + mf * 1024);
        #pragma unroll
        for (int nf = 0; nf < 4; ++nf)
            bfr[nf] = *(const bf16x8*)(cb + 16384 + b_off + nf * 1024);
        if (j + 3 < 16) GH_STAGE_A(j + 3, (j + 3) & 3);
        __builtin_amdgcn_s_barrier();
        asm volatile("s_waitcnt lgkmcnt(0)");
        __builtin_amdgcn_s_setprio(1);
        #pragma unroll
        for (int mf = 0; mf < 4; ++mf)
            #pragma unroll
            for (int nf = 0; nf < 4; ++nf)
                acc[mf][nf] = __builtin_amdgcn_mfma_f32_16x16x32_bf16(
                    af0[mf], bfr[nf], acc[mf][nf], 0, 0, 0);
        __builtin_amdgcn_s_setprio(0);
        __builtin_amdgcn_s_barrier();
        // ---- phase beta: A mf4-7 (B reused), stage B-half of tile j+3 ----
        #pragma unroll
        for (int mf = 0; mf < 4; ++mf)
            af1[mf] = *(const bf16x8*)(cb + a_off + (4 + mf) * 1024);
        if (j + 3 < 16) GH_STAGE_B(j + 3, (j + 3) & 3);
        if (j + 3 < 16)      asm volatile("s_waitcnt vmcnt(8)" ::: "memory");
        else if (j + 2 < 16) asm volatile("s_waitcnt vmcnt(4)" ::: "memory");
        else if (j + 1 < 16) asm volatile("s_waitcnt vmcnt(0)" ::: "memory");
        __builtin_amdgcn_s_barrier();
        asm volatile("s_waitcnt lgkmcnt(0)");
        __builtin_amdgcn_s_setprio(1);
        #pragma unroll
        for (int mf = 0; mf < 4; ++mf)
            #pragma unroll
            for (int nf = 0; nf < 4; ++nf)
                acc[4 + mf][nf] = __builtin_amdgcn_mfma_f32_16x16x32_bf16(
                    af1[mf], bfr[nf], acc[4 + mf][nf], 0, 0, 0);
        __builtin_amdgcn_s_setprio(0);
        __builtin_amdgcn_s_barrier();
    }
#undef GH_STAGE
#undef GH_STAGE_A
#undef GH_STAGE_B

    // ---- epilogue: 4 phases of 64 rows; acc rows = wm*128+mf*16+q*4+rg,
    //      cols = wn*64+nf*16+mi. Phase p rows: wm=p>>1, mf in (p&1)*4..+4.
    float* epi = (float*)smem_;
    if (ct == 8) {
        // qk tile: only cols 0..127 (wn<2) are real. stride 132 (f32).
        float* gbl = (float*)(smem_ + 33792);    // gamma[512] | beta[512]
        gbl[t] = gamma[t];
        gbl[t + 512] = beta[t];
        float bq4[4];
        #pragma unroll
        for (int nf = 0; nf < 4; ++nf)
            bq4[nf] = (wn < 2) ? bqk[wn * 64 + nf * 16 + mi] : 0.f;
        #pragma unroll
        for (int p = 0; p < 4; ++p) {
            if (wm == (p >> 1) && wn < 2) {
                #pragma unroll
                for (int m2 = 0; m2 < 4; ++m2) {
                    int mf = ((p & 1) << 2) + m2;
                    #pragma unroll
                    for (int nf = 0; nf < 4; ++nf)
                        #pragma unroll
                        for (int rg = 0; rg < 4; ++rg)
                            epi[(m2 * 16 + q * 4 + rg) * 132 + wn * 64 + nf * 16 + mi] =
                                silu_f(acc[mf][nf][rg] + bq4[nf]);
                }
            }
            __syncthreads();
            {   // heads 0..2: row-major [row][128]
                int lr = t >> 3, cs = (t & 7) * 16;
                float z[16];
                #pragma unroll
                for (int k = 0; k < 16; ++k) z[k] = epi[lr * 132 + cs + k];
                size_t growr = (size_t)(r0 + p * 64 + lr) * QKD + cs;
                #pragma unroll
                for (int hd = 0; hd < 3; ++hd) {
                    bfraw* arr = (hd == 0) ? qq : (hd == 1) ? lq : kk;
                    float tmp[16];
                    #pragma unroll
                    for (int k = 0; k < 16; ++k)
                        tmp[k] = z[k] * gbl[hd * 128 + cs + k] + gbl[512 + hd * 128 + cs + k];
                    store16bf(arr + growr, tmp);
                }
            }
            {   // head 3 -> lkT[bg][c][256] (block-local transpose)
                int c = t >> 2, jh = (t & 3) * 16;
                float g3 = gbl[384 + c], e3 = gbl[896 + c];
                float tmp[16];
                #pragma unroll
                for (int k = 0; k < 16; ++k)
                    tmp[k] = epi[(jh + k) * 132 + c] * g3 + e3;
                store16bf(lkT + ((size_t)by * QKD + c) * GRP + p * 64 + jh, tmp);
            }
            __syncthreads();
        }
        return;
    }
    float bias4[4];
    #pragma unroll
    for (int nf = 0; nf < 4; ++nf)
        bias4[nf] = bh[c0 + wn * 64 + nf * 16 + mi];
    if (ct < 4) {
        // v tile -> vT[bg][e][256] (block-local transpose). stride 257 (odd).
        #pragma unroll
        for (int p = 0; p < 4; ++p) {
            if (wm == (p >> 1)) {
                #pragma unroll
                for (int m2 = 0; m2 < 4; ++m2) {
                    int mf = ((p & 1) << 2) + m2;
                    #pragma unroll
                    for (int nf = 0; nf < 4; ++nf)
                        #pragma unroll
                        for (int rg = 0; rg < 4; ++rg)
                            epi[(m2 * 16 + q * 4 + rg) * 257 + wn * 64 + nf * 16 + mi] =
                                silu_f(acc[mf][nf][rg] + bias4[nf]);
                }
            }
            __syncthreads();
            int e2 = t >> 1, js = (t & 1) * 32;
            bfraw* dst = vT + ((size_t)by * HIDD + c0 + e2) * GRP + p * 64 + js;
            #pragma unroll
            for (int h2 = 0; h2 < 2; ++h2) {
                float tmp[16];
                #pragma unroll
                for (int k = 0; k < 16; ++k)
                    tmp[k] = epi[(js + h2 * 16 + k) * 257 + e2];
                store16bf(dst + h2 * 16, tmp);
            }
            __syncthreads();
        }
    } else {
        // gate tile: row-major copy-out. stride 260 (16B-aligned rows).
        #pragma unroll
        for (int p = 0; p < 4; ++p) {
            if (wm == (p >> 1)) {
                #pragma unroll
                for (int m2 = 0; m2 < 4; ++m2) {
                    int mf = ((p & 1) << 2) + m2;
                    #pragma unroll
                    for (int nf = 0; nf < 4; ++nf)
                        #pragma unroll
                        for (int rg = 0; rg < 4; ++rg)
                            epi[(m2 * 16 + q * 4 + rg) * 260 + wn * 64 + nf * 16 + mi] =
                                silu_f(acc[mf][nf][rg] + bias4[nf]);
                }
            }
            __syncthreads();
            int lr = t >> 3, cs = (t & 7) * 32;
            const float* src = epi + lr * 260 + cs;
            bfraw* dst = gate + (size_t)(r0 + p * 64 + lr) * HIDD + (c0 - HIDD) + cs;
            #pragma unroll
            for (int h2 = 0; h2 < 2; ++h2) {
                float tmp[16];
                #pragma unroll
                for (int k = 0; k < 16; ++k) tmp[k] = src[h2 * 16 + k];
                store16bf(dst + h2 * 16, tmp);
            }
            __syncthreads();
        }
    }
}

// ------------- fused sim + kv dispatch.
// blocks 0..511: kv; blocks 512..703: sim.
__global__ __launch_bounds__(256) void simkv_kernel(const bfraw* __restrict__ qq,
                                                    const bfraw* __restrict__ kk,
                                                    bfraw* __restrict__ attn,
                                                    const bfraw* __restrict__ vT,
                                                    const bfraw* __restrict__ lkT,
                                                    bfraw* __restrict__ kvT_raw) {
    SMEMP_DECL
    float* epi = (float*)smem_;
    int t = threadIdx.x;
    int lane = t & 63, wid = t >> 6;
    int wm = wid >> 1, wn = wid & 1;
    int q = lane >> 4, mi = lane & 15;
    int bid = blockIdx.x;
    f32x4 acc[4][4] = {};
    PIPE_DSTS
    if (bid < 512) {
        // ---- kv: kvT_raw[bg][e][d] = sum_j vT[bg][e][j] * lkT[bg][d][j] ----
        int bg = bid >> 3;
        int row0 = (bid & 7) * 128;
        PIPE_LOOP(8, vT + (size_t)bg * HIDD * GRP + (size_t)row0 * GRP, GRP,
                  lkT + (size_t)bg * QKD * GRP, GRP)
        bfraw* outg = kvT_raw + (size_t)bg * HIDD * QKD;
        #pragma unroll
        for (int p = 0; p < 4; ++p) {
            #pragma unroll
            for (int j = 0; j < 4; ++j)
                #pragma unroll
                for (int rg = 0; rg < 4; ++rg)
                    epi[(wm * 16 + q * 4 + rg) * EPIW + wn * 64 + j * 16 + mi] = acc[p][j][rg];
            __syncthreads();
            int lr = t >> 3, c0t = (t & 7) * 16;
            int gr = row0 + epi_row(p, lr);
            store16bf(outg + (size_t)gr * QKD + c0t, &epi[lr * EPIW + c0t]);
            __syncthreads();
        }
        return;
    }
    // ---- sim: attn[bg][i][j] = mask * relu(qq_i . kk_j / G)^2 ----
    int i = bid - 512;
    int bg = i & 63;
    int tid = i >> 6;
    int ry = (tid == 0) ? 0 : 1;
    int rx = (tid == 2) ? 1 : 0;
    int row0 = ry * 128, col0 = rx * 128;
    PIPE_LOOP(4, qq + (size_t)(bg * GRP + row0) * QKD, QKD,
              kk + (size_t)(bg * GRP + col0) * QKD, QKD)
    bfraw* ag = attn + (size_t)bg * GRP * GRP;
    #pragma unroll
    for (int p = 0; p < 4; ++p) {
        #pragma unroll
        for (int j = 0; j < 4; ++j) {
            int colg = col0 + wn * 64 + j * 16 + mi;
            #pragma unroll
            for (int rg = 0; rg < 4; ++rg) {
                int rowg = row0 + wm * 64 + p * 16 + q * 4 + rg;
                float s = acc[p][j][rg] * (1.f / GRP);
                s = fmaxf(s, 0.f);
                s = s * s;
                epi[(wm * 16 + q * 4 + rg) * EPIW + wn * 64 + j * 16 + mi] =
                    (colg > rowg) ? 0.f : s;
            }
        }
        __syncthreads();
        int lr = t >> 3, c0t = (t & 7) * 16;
        int gr = row0 + epi_row(p, lr);
        store16bf(ag + (size_t)gr * GRP + col0 + c0t, &epi[lr * EPIW + c0t]);
        __syncthreads();
    }
}

// ------------- exclusive cumsum over groups (with /G) -------------
__global__ __launch_bounds__(256) void cumsum2_kernel(const bfraw* __restrict__ raw,
                                                      bfraw* __restrict__ ex) {
    int idx = blockIdx.x * 256 + threadIdx.x;
    int b = idx >> 17;
    int r = idx & 131071;
    const bfraw* rp = raw + (size_t)b * NGRP * 131072 + r;
    bfraw* ep = ex + (size_t)b * NGRP * 131072 + r;
    float run = 0.f;
    #pragma unroll
    for (int g = 0; g < NGRP; ++g) {
        ep[(size_t)g * 131072] = f2bf(run);
        run += bf2f(rp[(size_t)g * 131072]) * (1.f / GRP);
    }
}

// ------------- gated = gate .* (attn@vv + lq@kv_ex)  (bf16 out) -------------
__global__ __launch_bounds__(256) void quadlin_mfma(const bfraw* __restrict__ attn,
                                                    const bfraw* __restrict__ vT,
                                                    const bfraw* __restrict__ lq,
                                                    const bfraw* __restrict__ kvT_ex,
                                                    const bfraw* __restrict__ gate,
                                                    bfraw* __restrict__ gated) {
    int bg = blockIdx.z;
    int row0 = blockIdx.y * 128;
    int col0 = blockIdx.x * 128;
    SMEMP_DECL
    float* epi = (float*)smem_;
    int t = threadIdx.x;
    int lane = t & 63, wid = t >> 6;
    int wm = wid >> 1, wn = wid & 1;
    int q = lane >> 4, mi = lane & 15;
    f32x4 acc[4][4] = {};
    PIPE_DSTS
    // Part 1: quadratic. A = attn rows (stride 256), BT = vT rows (stride 256).
    {
        int nit = (row0 + 128) >> 5;     // causal: attn[i][j]=0 for j>i
        PIPE_LOOP(nit, attn + (size_t)bg * GRP * GRP + (size_t)row0 * GRP, GRP,
                  vT + (size_t)bg * HIDD * GRP + (size_t)col0 * GRP, GRP)
    }
    // Part 2: linear. A = lq rows (stride 128), BT = kvT_ex rows (stride 128).
    PIPE_LOOP(4, lq + (size_t)(bg * GRP + row0) * QKD, QKD,
              kvT_ex + (size_t)bg * HIDD * QKD + (size_t)col0 * QKD, QKD)
    #pragma unroll
    for (int p = 0; p < 4; ++p) {
        #pragma unroll
        for (int j = 0; j < 4; ++j)
            #pragma unroll
            for (int rg = 0; rg < 4; ++rg)
                epi[(wm * 16 + q * 4 + rg) * EPIW + wn * 64 + j * 16 + mi] = acc[p][j][rg];
        __syncthreads();
        int lr = t >> 3, c0t = (t & 7) * 16;
        int gr = row0 + epi_row(p, lr);          // group-local row
        size_t grow = (size_t)bg * GRP + gr;
        const float* src = &epi[lr * EPIW + c0t];
        const bfraw* gsrc = gate + grow * HIDD + col0 + c0t;
        u16x8 g0 = *(const u16x8*)gsrc;
        u16x8 g1 = *(const u16x8*)(gsrc + 8);
        float tmp[16];
        #pragma unroll
        for (int k = 0; k < 8; ++k) tmp[k] = src[k] * bf2f(g0[k]);
        #pragma unroll
        for (int k = 0; k < 8; ++k) tmp[8 + k] = src[8 + k] * bf2f(g1[k]);
        store16bf(gated + grow * HIDD + col0 + c0t, tmp);
        __syncthreads();
    }
}

// ------------- final: out = gated @ WoT^T + bo + x  (fp32 out) -------------
__global__ __launch_bounds__(256) void gemm_final(const bfraw* __restrict__ A,
                                                  const bfraw* __restrict__ BT,
                                                  const float* __restrict__ bo,
                                                  const float* __restrict__ x,
                                                  float* __restrict__ out) {
    SMEMP_DECL
    float* epi = (float*)smem_;
    int t = threadIdx.x;
    int lane = t & 63, wid = t >> 6;
    int wm = wid >> 1, wn = wid & 1;
    int q = lane >> 4, mi = lane & 15;
    int row0 = blockIdx.y * 128, col0 = blockIdx.x * 128;
    f32x4 acc[4][4] = {};
    PIPE_DSTS
    PIPE_LOOP(32, A + (size_t)row0 * HIDD, HIDD, BT + (size_t)col0 * HIDD, HIDD)
    #pragma unroll
    for (int p = 0; p < 4; ++p) {
        #pragma unroll
        for (int j = 0; j < 4; ++j) {
            float bv = bo[col0 + wn * 64 + j * 16 + mi];
            #pragma unroll
            for (int rg = 0; rg < 4; ++rg)
                epi[(wm * 16 + q * 4 + rg) * EPIW + wn * 64 + j * 16 + mi] =
                    acc[p][j][rg] + bv;
        }
        __syncthreads();
        int lr = t >> 3, c0t = (t & 7) * 16;
        int gr = row0 + epi_row(p, lr);
        const float* src = &epi[lr * EPIW + c0t];
        const float* xsrc = x + (size_t)gr * DIMD + col0 + c0t;
        float* dst = out + (size_t)gr * DIMD + col0 + c0t;
        #pragma unroll
        for (int v = 0; v < 4; ++v) {
            float4 a = ((const float4*)src)[v];
            float4 xv = ((const float4*)xsrc)[v];
            a.x += xv.x; a.y += xv.y; a.z += xv.z; a.w += xv.w;
            ((float4*)dst)[v] = a;
        }
        __syncthreads();
    }
}

extern "C" void kernel_launch(void* const* d_in, const int* in_sizes, int n_in,
                              void* d_out, int out_size, void* d_ws, size_t ws_size,
                              hipStream_t stream) {
    const float* x     = (const float*)d_in[0];
    const float* ln_w  = (const float*)d_in[1];
    const float* ln_b  = (const float*)d_in[2];
    const float* Wh    = (const float*)d_in[3];
    const float* bh    = (const float*)d_in[4];
    const float* Wqk   = (const float*)d_in[5];
    const float* bqk   = (const float*)d_in[6];
    const float* gamma = (const float*)d_in[7];
    const float* beta  = (const float*)d_in[8];
    const float* Wo    = (const float*)d_in[9];
    const float* bo    = (const float*)d_in[10];
    float* out = (float*)d_out;

    // d_out (32 MiB) hosts short-lived buffers; all dead before gemm_final writes out.
    char* outb_ = (char*)d_out;
    bfraw* attn = (bfraw*)(outb_);                    //  8 MiB [64][256][256]
    bfraw* qq   = (bfraw*)(outb_ + 8388608);          //  4 MiB [16384][128]
    bfraw* kk   = (bfraw*)(outb_ + 12582912);         //  4 MiB
    bfraw* lq   = (bfraw*)(outb_ + 16777216);         //  4 MiB
    bfraw* WhT  = (bfraw*)(outb_ + 20971520);         //  2 MiB [2048][512]
    bfraw* WqkT = (bfraw*)(outb_ + 23068672);         //  128 KiB [128][512]

    // ws layout (byte offsets):
    char* wsb = (char*)d_ws;
    bfraw* vT      = (bfraw*)(wsb);                   // 32 MiB [64][1024][256]
    bfraw* gate    = (bfraw*)(wsb + 33554432);        // 32 MiB [16384][1024]
    bfraw* gated   = (bfraw*)(wsb + 67108864);        // 32 MiB [16384][1024]
    bfraw* normb   = (bfraw*)(wsb + 100663296);       // 16 MiB [16384][512]
    bfraw* kvT_raw = (bfraw*)(wsb + 117440512);       // 16 MiB [64][1024][128]
    bfraw* kvT_ex  = (bfraw*)(wsb + 134217728);       // 16 MiB [64][1024][128]
    bfraw* lkT     = (bfraw*)(wsb + 150994944);       //  4 MiB [64][128][256]
    bfraw* WoT     = (bfraw*)(wsb + 155189248);       //  1 MiB [512][1024]

    // 1. prep: LayerNorm + all weight transposes (one dispatch)
    prep_kernel<<<4096 + 1024 + 512 + 64, 256, 0, stream>>>(
        x, ln_w, ln_b, Wh, Wo, Wqk, normb, WhT, WoT, WqkT);
    // 2. merged h+qk GEMM (256^2 2-phase pipelined engine): vT + gate + qq/lq/kk/lkT
    gemm_h256<<<576, 512, 0, stream>>>(
        normb, WhT, WqkT, bh, bqk, gamma, beta, vT, gate, qq, lq, kk, lkT);
    // 3. fused kv + sim (one dispatch; kv blocks first)
    simkv_kernel<<<512 + 192, 256, 0, stream>>>(qq, kk, attn, vT, lkT, kvT_raw);
    // 4. exclusive cumsum over groups (with /G) -> kvT_ex
    cumsum2_kernel<<<(BATCH * QKD * HIDD) / 256, 256, 0, stream>>>(kvT_raw, kvT_ex);
    // 5. gated = gate .* (attn@vv + lq@kv_ex)
    quadlin_mfma<<<dim3(HIDD / 128, GRP / 128, BGRP), 256, 0, stream>>>(
        attn, vT, lq, kvT_ex, gate, gated);
    // 6. out = gated @ Wo + bo + x
    gemm_final<<<dim3(DIMD / 128, TROWS / 128), 256, 0, stream>>>(gated, WoT, bo, x, out);
}

// Round 3
// 272.876 us; speedup vs baseline: 1.2488x; 1.2488x over previous
//
#include <hip/hip_runtime.h>
#include <hip/hip_bf16.h>
#include <math.h>

// FLASH (GAU-style) fused block. Round 13: R12's 2-phase split reverted (it
// doubled gemm_h256 — barrier latency fully exposed at 2 waves/SIMD).
// gemm_h256 now runs 1024 threads / 16 waves (4x4 wave grid, 64x64 per wave,
// acc[4][4] = 64 VGPR) -> 4 waves/SIMD of intra-block overlap. Same 256^2
// tile, same verified XOR-swizzle, same 4-slot LDS ring + counted vmcnt
// (counts halved: 2 gloads/thread/step). Epilogues remapped for 1024 threads.
// b=4, n=4096, dim=512, hid=1024, qk=128, group=256.

#define BATCH 4
#define SEQ   4096
#define TROWS 16384      // BATCH*SEQ
#define DIMD  512
#define HIDD  1024
#define QKD   128
#define GRP   256
#define NGRP  16         // SEQ/GRP
#define BGRP  64         // BATCH*NGRP
#define EPIW  132        // padded LDS epilogue row stride (f32 path, 128-tiles)
#define EPB   130        // bf16 full-tile epilogue row stride (shorts)

typedef unsigned short bfraw;
typedef __attribute__((ext_vector_type(8))) short bf16x8;
typedef __attribute__((ext_vector_type(8))) unsigned short u16x8;
typedef __attribute__((ext_vector_type(4))) unsigned int u32x4;
typedef __attribute__((ext_vector_type(4))) float f32x4;

__device__ __forceinline__ float bf2f(bfraw u) {
    union { float f; unsigned int i; } c;
    c.i = ((unsigned int)u) << 16;
    return c.f;
}
__device__ __forceinline__ bfraw f2bf(float f) {
    unsigned int x = __float_as_uint(f);
    unsigned int r = (x + 0x7fffu + ((x >> 16) & 1u)) >> 16;   // RNE
    return (bfraw)r;
}
__device__ __forceinline__ unsigned int pkbf(float lo, float hi) {
    __hip_bfloat162 h2 = __float22bfloat162_rn(make_float2(lo, hi));
    union { __hip_bfloat162 h; unsigned int u; } c; c.h = h2;
    return c.u;
}
// 16 contiguous f32 -> 16 bf16 at dst (two 16B stores), packed cvt.
__device__ __forceinline__ void store16bf(bfraw* dst, const float* src) {
    u32x4 a, b;
    #pragma unroll
    for (int k = 0; k < 4; ++k) a[k] = pkbf(src[2 * k], src[2 * k + 1]);
    #pragma unroll
    for (int k = 0; k < 4; ++k) b[k] = pkbf(src[8 + 2 * k], src[8 + 2 * k + 1]);
    *(u32x4*)dst = a;
    *(u32x4*)(dst + 8) = b;
}
__device__ __forceinline__ float silu_f(float z) {
    return z / (1.f + __expf(-z));
}
__device__ __forceinline__ void gload_lds16(const void* g, void* l) {
    __builtin_amdgcn_global_load_lds(
        (const __attribute__((address_space(1))) unsigned int*)g,
        (__attribute__((address_space(3))) unsigned int*)l, 16, 0, 0);
}

// ===================== legacy 128^2 engine (other kernels) =====================
// One BK=32 MFMA step on staged tiles (4 waves, each 64x64 = 4x4 frags).
__device__ __forceinline__ void mfma_step(const bfraw* As, const bfraw* Bs,
                                          f32x4 acc[4][4], int wm, int wn,
                                          int q, int mi) {
    bf16x8 af[4], bfg[4];
    #pragma unroll
    for (int i = 0; i < 4; ++i)
        af[i] = *(const bf16x8*)&As[(size_t)(wm * 64 + i * 16 + mi) * 32 + q * 8];
    #pragma unroll
    for (int j = 0; j < 4; ++j)
        bfg[j] = *(const bf16x8*)&Bs[(size_t)(wn * 64 + j * 16 + mi) * 32 + q * 8];
    #pragma unroll
    for (int i = 0; i < 4; ++i)
        #pragma unroll
        for (int j = 0; j < 4; ++j)
            acc[i][j] = __builtin_amdgcn_mfma_f32_16x16x32_bf16(af[i], bfg[j], acc[i][j], 0, 0, 0);
}

// Double-buffered pipelined K-loop. 33280 bytes: 2x(A 8KB + B 8KB) + epi overlay.
#define SMEMP_DECL                                              \
    __shared__ __align__(16) char smem_[33280];                 \
    bfraw* A0buf = (bfraw*)smem_;                               \
    bfraw* B0buf = (bfraw*)(smem_ + 8192);                      \
    bfraw* A1buf = (bfraw*)(smem_ + 16384);                     \
    bfraw* B1buf = (bfraw*)(smem_ + 24576);

#define PIPE_DSTS                                               \
    bfraw* a0d  = A0buf + wid * 512;                            \
    bfraw* a0d2 = A0buf + 2048 + wid * 512;                     \
    bfraw* b0d  = B0buf + wid * 512;                            \
    bfraw* b0d2 = B0buf + 2048 + wid * 512;                     \
    bfraw* a1d  = A1buf + wid * 512;                            \
    bfraw* a1d2 = A1buf + 2048 + wid * 512;                     \
    bfraw* b1d  = B1buf + wid * 512;                            \
    bfraw* b1d2 = B1buf + 2048 + wid * 512;

#define KLOOP_PRE(Abase, Astr, Bbase, Bstr)                                    \
    const bfraw* pa0 = (Abase) + (size_t)(t >> 2) * (Astr) + (t & 3) * 8;      \
    const bfraw* pa1 = pa0 + (size_t)64 * (Astr);                              \
    const bfraw* pb0 = (Bbase) + (size_t)(t >> 2) * (Bstr) + (t & 3) * 8;      \
    const bfraw* pb1 = pb0 + (size_t)64 * (Bstr);

#define STAGE0                                                                 \
    do { gload_lds16(pa0, a0d); gload_lds16(pa1, a0d2);                        \
         gload_lds16(pb0, b0d); gload_lds16(pb1, b0d2);                        \
         pa0 += 32; pa1 += 32; pb0 += 32; pb1 += 32; } while (0)
#define STAGE1                                                                 \
    do { gload_lds16(pa0, a1d); gload_lds16(pa1, a1d2);                        \
         gload_lds16(pb0, b1d); gload_lds16(pb1, b1d2);                        \
         pa0 += 32; pa1 += 32; pb0 += 32; pb1 += 32; } while (0)

// NIT must be even (all call sites: K/32 ∈ {4,8,16,32}).
#define PIPE_LOOP(NIT, Abase, Astr, Bbase, Bstr)                               \
    {                                                                          \
        KLOOP_PRE(Abase, Astr, Bbase, Bstr)                                    \
        STAGE0;                                                                \
        for (int it = 0; it < (NIT); it += 2) {                                \
            __syncthreads();                                                   \
            if (it + 1 < (NIT)) STAGE1;                                        \
            mfma_step(A0buf, B0buf, acc, wm, wn, q, mi);                       \
            __syncthreads();                                                   \
            if (it + 2 < (NIT)) STAGE0;                                        \
            if (it + 1 < (NIT))                                                \
                mfma_step(A1buf, B1buf, acc, wm, wn, q, mi);                   \
        }                                                                      \
        __syncthreads();                                                       \
    }

__device__ __forceinline__ int epi_row(int p, int lr) {
    return (lr < 16) ? (p * 16 + lr) : (64 + p * 16 + (lr - 16));
}

// ------------- prep: ln (blocks 0..4095) + 3 weight transposes -------------
__global__ __launch_bounds__(256) void prep_kernel(const float* __restrict__ x,
                                                   const float* __restrict__ lnw,
                                                   const float* __restrict__ lnb,
                                                   const float* __restrict__ Wh,
                                                   const float* __restrict__ Wo,
                                                   const float* __restrict__ Wqk,
                                                   bfraw* __restrict__ normb,
                                                   bfraw* __restrict__ WhT,
                                                   bfraw* __restrict__ WoT,
                                                   bfraw* __restrict__ WqkT) {
    __shared__ float tile[32][33];
    int bid = blockIdx.x;
    int t = threadIdx.x;
    if (bid < 4096) {
        int row  = bid * 4 + (t >> 6);
        int lane = t & 63;
        const float* xr = x + (size_t)row * DIMD;
        float4 v0 = ((const float4*)xr)[lane];
        float4 v1 = ((const float4*)xr)[lane + 64];
        float s  = v0.x + v0.y + v0.z + v0.w + v1.x + v1.y + v1.z + v1.w;
        float ss = v0.x*v0.x + v0.y*v0.y + v0.z*v0.z + v0.w*v0.w
                 + v1.x*v1.x + v1.y*v1.y + v1.z*v1.z + v1.w*v1.w;
        #pragma unroll
        for (int off = 32; off; off >>= 1) {
            s  += __shfl_xor(s, off);
            ss += __shfl_xor(ss, off);
        }
        float mu  = s * (1.f / DIMD);
        float var = ss * (1.f / DIMD) - mu * mu;
        float inv = rsqrtf(var + 1e-5f);
        float4 w0 = ((const float4*)lnw)[lane],  w1 = ((const float4*)lnw)[lane + 64];
        float4 b0 = ((const float4*)lnb)[lane],  b1 = ((const float4*)lnb)[lane + 64];
        unsigned int o0 = pkbf((v0.x - mu) * inv * w0.x + b0.x,
                               (v0.y - mu) * inv * w0.y + b0.y);
        unsigned int o1 = pkbf((v0.z - mu) * inv * w0.z + b0.z,
                               (v0.w - mu) * inv * w0.w + b0.w);
        unsigned int o2 = pkbf((v1.x - mu) * inv * w1.x + b1.x,
                               (v1.y - mu) * inv * w1.y + b1.y);
        unsigned int o3 = pkbf((v1.z - mu) * inv * w1.z + b1.z,
                               (v1.w - mu) * inv * w1.w + b1.w);
        unsigned int* brow = (unsigned int*)(normb + (size_t)row * DIMD);
        ((uint2*)brow)[lane]      = make_uint2(o0, o1);
        ((uint2*)brow)[lane + 64] = make_uint2(o2, o3);
        return;
    }
    bid -= 4096;
    const float* in; bfraw* outp; int R, C, nx;
    if (bid < 1024)      { in = Wh;  outp = WhT;  R = DIMD; C = 2 * HIDD; nx = 64; }
    else if (bid < 1536) { bid -= 1024; in = Wo;  outp = WoT;  R = HIDD; C = DIMD; nx = 16; }
    else                 { bid -= 1536; in = Wqk; outp = WqkT; R = DIMD; C = QKD;  nx = 4; }
    int c0 = (bid % nx) * 32, r0 = (bid / nx) * 32;
    int tr = t >> 3, tc4 = (t & 7) * 4;
    float4 v = *(const float4*)&in[(size_t)(r0 + tr) * C + c0 + tc4];
    tile[tr][tc4 + 0] = v.x; tile[tr][tc4 + 1] = v.y;
    tile[tr][tc4 + 2] = v.z; tile[tr][tc4 + 3] = v.w;
    __syncthreads();
    ushort4 s;
    s.x = f2bf(tile[tc4 + 0][tr]);
    s.y = f2bf(tile[tc4 + 1][tr]);
    s.z = f2bf(tile[tc4 + 2][tr]);
    s.w = f2bf(tile[tc4 + 3][tr]);
    *(ushort4*)&outp[(size_t)(c0 + tr) * R + r0 + tc4] = s;
}

// ============ 256^2, 16-wave (1024-thr), 4-slot-ring h+qk GEMM ============
// Grid: 576 blocks (XCD-bijective swizzle -> (ct 0..8, by 0..63)), 1024 thr.
// Wave grid 4M x 4N; per-wave output 64x64 (acc[4][4] = 64 VGPR) -> 4 waves
// per SIMD of intra-block latency hiding. LDS: 4 slots x (A 16K + B 16K) =
// 128 KiB; epilogue overlays. Per K-step: 8 swizzled ds_read_b128, 2 gloads
// (tile j+3), 16 MFMA under setprio, counted vmcnt(4), one barrier.
__global__ __launch_bounds__(1024, 4) void gemm_h256(
    const bfraw* __restrict__ A,      // normb [16384][512]
    const bfraw* __restrict__ WhT,    // [2048][512]
    const bfraw* __restrict__ WqkT,   // [128][512]
    const float* __restrict__ bh,     // [2048]
    const float* __restrict__ bqk,    // [128]
    const float* __restrict__ gamma,  // [4][128]
    const float* __restrict__ beta,   // [4][128]
    bfraw* __restrict__ vT,
    bfraw* __restrict__ gate,
    bfraw* __restrict__ qq,
    bfraw* __restrict__ lq,
    bfraw* __restrict__ kk,
    bfraw* __restrict__ lkT) {
    __shared__ __align__(16) char smem_[131072];
    const int t = threadIdx.x;
    const int lane = t & 63, wid = t >> 6;
    const int wm = wid >> 2, wn = wid & 3;       // 4 x 4 wave grid
    const int q = lane >> 4, mi = lane & 15;
    // XCD-bijective swizzle: 576 = 72*8; same-by column tiles stay on one XCD.
    int nid = (blockIdx.x & 7) * 72 + (blockIdx.x >> 3);
    const int ct = nid % 9, by = nid / 9;
    const int r0 = by * 256, c0 = ct * 256;

    // ---- staging: pre-swizzled global sources, linear LDS dests ----
    // Tile region 16KB = 128 lines x 128B; line l holds rows 2l,2l+1 (64B ea).
    // Physical slot p at line l holds logical slot lslot = p ^ (l&7);
    // lslot>>2 = row parity, (lslot&3)*8 = k-offset. Thread t covers byte
    // t*16: line = t>>3, pslot = t&7.
    const int lslot = (t & 7) ^ ((t >> 3) & 7);
    const int srow  = 2 * (t >> 3) + (lslot >> 2);      // 0..255
    const int skel  = (lslot & 3) * 8;
    const bfraw* Asrc = A + (size_t)(r0 + srow) * DIMD + skel;
    const bfraw* Bsrc;
    if (ct < 8) {
        Bsrc = WhT + (size_t)(c0 + srow) * DIMD + skel;
    } else {
        Bsrc = WqkT + (size_t)(srow & 127) * DIMD + skel;  // rows 128.. dup
    }
    // ---- swizzled LDS read offsets (same verified involution) ----
    const int swz = ((((mi & 1) << 2) | q) ^ ((mi >> 1) & 7)) << 4;
    const int a_off = (wm * 32 + (mi >> 1)) * 128 + swz;            // 64 rows/wm
    const int b_off = (wn * 32 + (mi >> 1)) * 128 + swz;

#define GH_STAGE(KT, SLOT)                                                    \
    do {                                                                      \
        char* sb_ = smem_ + (SLOT) * 32768;                                   \
        gload_lds16(Asrc + (KT) * 32, sb_ + t * 16);                          \
        gload_lds16(Bsrc + (KT) * 32, sb_ + 16384 + t * 16);                  \
    } while (0)

    f32x4 acc[4][4] = {};
    GH_STAGE(0, 0);
    GH_STAGE(1, 1);
    GH_STAGE(2, 2);
    asm volatile("s_waitcnt vmcnt(4)" ::: "memory");
    __builtin_amdgcn_s_barrier();

    #pragma unroll
    for (int j = 0; j < 16; ++j) {
        const char* cb = smem_ + (j & 3) * 32768;
        bf16x8 af[4], bfr[4];
        #pragma unroll
        for (int mf = 0; mf < 4; ++mf)
            af[mf] = *(const bf16x8*)(cb + a_off + mf * 1024);
        #pragma unroll
        for (int nf = 0; nf < 4; ++nf)
            bfr[nf] = *(const bf16x8*)(cb + 16384 + b_off + nf * 1024);
        if (j + 3 < 16) GH_STAGE(j + 3, (j + 3) & 3);
        __builtin_amdgcn_s_setprio(1);
        #pragma unroll
        for (int mf = 0; mf < 4; ++mf)
            #pragma unroll
            for (int nf = 0; nf < 4; ++nf)
                acc[mf][nf] = __builtin_amdgcn_mfma_f32_16x16x32_bf16(
                    af[mf], bfr[nf], acc[mf][nf], 0, 0, 0);
        __builtin_amdgcn_s_setprio(0);
        if (j + 3 < 16)      asm volatile("s_waitcnt vmcnt(4)" ::: "memory");
        else if (j + 2 < 16) asm volatile("s_waitcnt vmcnt(2)" ::: "memory");
        else if (j + 1 < 16) asm volatile("s_waitcnt vmcnt(0)" ::: "memory");
        __builtin_amdgcn_s_barrier();
    }
#undef GH_STAGE

    // ---- epilogue: 4 phases of 64 rows; phase p written by waves wm==p.
    //      acc row (in phase) = mf*16 + q*4 + rg; col = wn*64 + nf*16 + mi.
    float* epi = (float*)smem_;
    if (ct == 8) {
        // qk tile: only cols 0..127 (wn<2) real. stride 132 (f32).
        float* gbl = (float*)(smem_ + 67584);    // gamma[512] | beta[512]
        if (t < 512) { gbl[t] = gamma[t]; gbl[t + 512] = beta[t]; }
        float bq4[4];
        #pragma unroll
        for (int nf = 0; nf < 4; ++nf)
            bq4[nf] = (wn < 2) ? bqk[wn * 64 + nf * 16 + mi] : 0.f;
        #pragma unroll
        for (int p = 0; p < 4; ++p) {
            if (wm == p && wn < 2) {
                #pragma unroll
                for (int mf = 0; mf < 4; ++mf)
                    #pragma unroll
                    for (int nf = 0; nf < 4; ++nf)
                        #pragma unroll
                        for (int rg = 0; rg < 4; ++rg)
                            epi[(mf * 16 + q * 4 + rg) * 132 + wn * 64 + nf * 16 + mi] =
                                silu_f(acc[mf][nf][rg] + bq4[nf]);
            }
            __syncthreads();
            if (t < 512) {   // heads 0..2: row-major [row][128]
                int lr = t >> 3, cs = (t & 7) * 16;
                float z[16];
                #pragma unroll
                for (int k = 0; k < 16; ++k) z[k] = epi[lr * 132 + cs + k];
                size_t growr = (size_t)(r0 + p * 64 + lr) * QKD + cs;
                #pragma unroll
                for (int hd = 0; hd < 3; ++hd) {
                    bfraw* arr = (hd == 0) ? qq : (hd == 1) ? lq : kk;
                    float tmp[16];
                    #pragma unroll
                    for (int k = 0; k < 16; ++k)
                        tmp[k] = z[k] * gbl[hd * 128 + cs + k] + gbl[512 + hd * 128 + cs + k];
                    store16bf(arr + growr, tmp);
                }
            } else {         // head 3 -> lkT[bg][c][256] (block-local transpose)
                int tt = t - 512;
                int c = tt >> 2, jh = (tt & 3) * 16;
                float g3 = gbl[384 + c], e3 = gbl[896 + c];
                float tmp[16];
                #pragma unroll
                for (int k = 0; k < 16; ++k)
                    tmp[k] = epi[(jh + k) * 132 + c] * g3 + e3;
                store16bf(lkT + ((size_t)by * QKD + c) * GRP + p * 64 + jh, tmp);
            }
            __syncthreads();
        }
        return;
    }
    float bias4[4];
    #pragma unroll
    for (int nf = 0; nf < 4; ++nf)
        bias4[nf] = bh[c0 + wn * 64 + nf * 16 + mi];
    if (ct < 4) {
        // v tile -> vT[bg][e][256] (block-local transpose). stride 257 (odd).
        #pragma unroll
        for (int p = 0; p < 4; ++p) {
            if (wm == p) {
                #pragma unroll
                for (int mf = 0; mf < 4; ++mf)
                    #pragma unroll
                    for (int nf = 0; nf < 4; ++nf)
                        #pragma unroll
                        for (int rg = 0; rg < 4; ++rg)
                            epi[(mf * 16 + q * 4 + rg) * 257 + wn * 64 + nf * 16 + mi] =
                                silu_f(acc[mf][nf][rg] + bias4[nf]);
            }
            __syncthreads();
            int e2 = t >> 2, js = (t & 3) * 16;
            float tmp[16];
            #pragma unroll
            for (int k = 0; k < 16; ++k)
                tmp[k] = epi[(js + k) * 257 + e2];
            store16bf(vT + ((size_t)by * HIDD + c0 + e2) * GRP + p * 64 + js, tmp);
            __syncthreads();
        }
    } else {
        // gate tile: row-major copy-out. stride 260 (16B-aligned rows).
        #pragma unroll
        for (int p = 0; p < 4; ++p) {
            if (wm == p) {
                #pragma unroll
                for (int mf = 0; mf < 4; ++mf)
                    #pragma unroll
                    for (int nf = 0; nf < 4; ++nf)
                        #pragma unroll
                        for (int rg = 0; rg < 4; ++rg)
                            epi[(mf * 16 + q * 4 + rg) * 260 + wn * 64 + nf * 16 + mi] =
                                silu_f(acc[mf][nf][rg] + bias4[nf]);
            }
            __syncthreads();
            int lr = t >> 4, cs = (t & 15) * 16;
            float tmp[16];
            #pragma unroll
            for (int k = 0; k < 16; ++k)
                tmp[k] = epi[lr * 260 + cs + k];
            store16bf(gate + (size_t)(r0 + p * 64 + lr) * HIDD + (c0 - HIDD) + cs, tmp);
            __syncthreads();
        }
    }
}

// ------------- fused sim + kv dispatch.
// blocks 0..511: kv; blocks 512..703: sim.
__global__ __launch_bounds__(256) void simkv_kernel(const bfraw* __restrict__ qq,
                                                    const bfraw* __restrict__ kk,
                                                    bfraw* __restrict__ attn,
                                                    const bfraw* __restrict__ vT,
                                                    const bfraw* __restrict__ lkT,
                                                    bfraw* __restrict__ kvT_raw) {
    SMEMP_DECL
    float* epi = (float*)smem_;
    int t = threadIdx.x;
    int lane = t & 63, wid = t >> 6;
    int wm = wid >> 1, wn = wid & 1;
    int q = lane >> 4, mi = lane & 15;
    int bid = blockIdx.x;
    f32x4 acc[4][4] = {};
    PIPE_DSTS
    if (bid < 512) {
        // ---- kv: kvT_raw[bg][e][d] = sum_j vT[bg][e][j] * lkT[bg][d][j] ----
        int bg = bid >> 3;
        int row0 = (bid & 7) * 128;
        PIPE_LOOP(8, vT + (size_t)bg * HIDD * GRP + (size_t)row0 * GRP, GRP,
                  lkT + (size_t)bg * QKD * GRP, GRP)
        bfraw* outg = kvT_raw + (size_t)bg * HIDD * QKD;
        #pragma unroll
        for (int p = 0; p < 4; ++p) {
            #pragma unroll
            for (int j = 0; j < 4; ++j)
                #pragma unroll
                for (int rg = 0; rg < 4; ++rg)
                    epi[(wm * 16 + q * 4 + rg) * EPIW + wn * 64 + j * 16 + mi] = acc[p][j][rg];
            __syncthreads();
            int lr = t >> 3, c0t = (t & 7) * 16;
            int gr = row0 + epi_row(p, lr);
            store16bf(outg + (size_t)gr * QKD + c0t, &epi[lr * EPIW + c0t]);
            __syncthreads();
        }
        return;
    }
    // ---- sim: attn[bg][i][j] = mask * relu(qq_i . kk_j / G)^2 ----
    int i = bid - 512;
    int bg = i & 63;
    int tid = i >> 6;
    int ry = (tid == 0) ? 0 : 1;
    int rx = (tid == 2) ? 1 : 0;
    int row0 = ry * 128, col0 = rx * 128;
    PIPE_LOOP(4, qq + (size_t)(bg * GRP + row0) * QKD, QKD,
              kk + (size_t)(bg * GRP + col0) * QKD, QKD)
    bfraw* ag = attn + (size_t)bg * GRP * GRP;
    #pragma unroll
    for (int p = 0; p < 4; ++p) {
        #pragma unroll
        for (int j = 0; j < 4; ++j) {
            int colg = col0 + wn * 64 + j * 16 + mi;
            #pragma unroll
            for (int rg = 0; rg < 4; ++rg) {
                int rowg = row0 + wm * 64 + p * 16 + q * 4 + rg;
                float s = acc[p][j][rg] * (1.f / GRP);
                s = fmaxf(s, 0.f);
                s = s * s;
                epi[(wm * 16 + q * 4 + rg) * EPIW + wn * 64 + j * 16 + mi] =
                    (colg > rowg) ? 0.f : s;
            }
        }
        __syncthreads();
        int lr = t >> 3, c0t = (t & 7) * 16;
        int gr = row0 + epi_row(p, lr);
        store16bf(ag + (size_t)gr * GRP + col0 + c0t, &epi[lr * EPIW + c0t]);
        __syncthreads();
    }
}

// ------------- exclusive cumsum over groups (with /G) -------------
__global__ __launch_bounds__(256) void cumsum2_kernel(const bfraw* __restrict__ raw,
                                                      bfraw* __restrict__ ex) {
    int idx = blockIdx.x * 256 + threadIdx.x;
    int b = idx >> 17;
    int r = idx & 131071;
    const bfraw* rp = raw + (size_t)b * NGRP * 131072 + r;
    bfraw* ep = ex + (size_t)b * NGRP * 131072 + r;
    float run = 0.f;
    #pragma unroll
    for (int g = 0; g < NGRP; ++g) {
        ep[(size_t)g * 131072] = f2bf(run);
        run += bf2f(rp[(size_t)g * 131072]) * (1.f / GRP);
    }
}

// ------------- gated = gate .* (attn@vv + lq@kv_ex)  (bf16 out) -------------
__global__ __launch_bounds__(256) void quadlin_mfma(const bfraw* __restrict__ attn,
                                                    const bfraw* __restrict__ vT,
                                                    const bfraw* __restrict__ lq,
                                                    const bfraw* __restrict__ kvT_ex,
                                                    const bfraw* __restrict__ gate,
                                                    bfraw* __restrict__ gated) {
    int bg = blockIdx.z;
    int row0 = blockIdx.y * 128;
    int col0 = blockIdx.x * 128;
    SMEMP_DECL
    float* epi = (float*)smem_;
    int t = threadIdx.x;
    int lane = t & 63, wid = t >> 6;
    int wm = wid >> 1, wn = wid & 1;
    int q = lane >> 4, mi = lane & 15;
    f32x4 acc[4][4] = {};
    PIPE_DSTS
    // Part 1: quadratic. A = attn rows (stride 256), BT = vT rows (stride 256).
    {
        int nit = (row0 + 128) >> 5;     // causal: attn[i][j]=0 for j>i
        PIPE_LOOP(nit, attn + (size_t)bg * GRP * GRP + (size_t)row0 * GRP, GRP,
                  vT + (size_t)bg * HIDD * GRP + (size_t)col0 * GRP, GRP)
    }
    // Part 2: linear. A = lq rows (stride 128), BT = kvT_ex rows (stride 128).
    PIPE_LOOP(4, lq + (size_t)(bg * GRP + row0) * QKD, QKD,
              kvT_ex + (size_t)bg * HIDD * QKD + (size_t)col0 * QKD, QKD)
    #pragma unroll
    for (int p = 0; p < 4; ++p) {
        #pragma unroll
        for (int j = 0; j < 4; ++j)
            #pragma unroll
            for (int rg = 0; rg < 4; ++rg)
                epi[(wm * 16 + q * 4 + rg) * EPIW + wn * 64 + j * 16 + mi] = acc[p][j][rg];
        __syncthreads();
        int lr = t >> 3, c0t = (t & 7) * 16;
        int gr = row0 + epi_row(p, lr);          // group-local row
        size_t grow = (size_t)bg * GRP + gr;
        const float* src = &epi[lr * EPIW + c0t];
        const bfraw* gsrc = gate + grow * HIDD + col0 + c0t;
        u16x8 g0 = *(const u16x8*)gsrc;
        u16x8 g1 = *(const u16x8*)(gsrc + 8);
        float tmp[16];
        #pragma unroll
        for (int k = 0; k < 8; ++k) tmp[k] = src[k] * bf2f(g0[k]);
        #pragma unroll
        for (int k = 0; k < 8; ++k) tmp[8 + k] = src[8 + k] * bf2f(g1[k]);
        store16bf(gated + grow * HIDD + col0 + c0t, tmp);
        __syncthreads();
    }
}

// ------------- final: out = gated @ WoT^T + bo + x  (fp32 out) -------------
__global__ __launch_bounds__(256) void gemm_final(const bfraw* __restrict__ A,
                                                  const bfraw* __restrict__ BT,
                                                  const float* __restrict__ bo,
                                                  const float* __restrict__ x,
                                                  float* __restrict__ out) {
    SMEMP_DECL
    float* epi = (float*)smem_;
    int t = threadIdx.x;
    int lane = t & 63, wid = t >> 6;
    int wm = wid >> 1, wn = wid & 1;
    int q = lane >> 4, mi = lane & 15;
    int row0 = blockIdx.y * 128, col0 = blockIdx.x * 128;
    f32x4 acc[4][4] = {};
    PIPE_DSTS
    PIPE_LOOP(32, A + (size_t)row0 * HIDD, HIDD, BT + (size_t)col0 * HIDD, HIDD)
    #pragma unroll
    for (int p = 0; p < 4; ++p) {
        #pragma unroll
        for (int j = 0; j < 4; ++j) {
            float bv = bo[col0 + wn * 64 + j * 16 + mi];
            #pragma unroll
            for (int rg = 0; rg < 4; ++rg)
                epi[(wm * 16 + q * 4 + rg) * EPIW + wn * 64 + j * 16 + mi] =
                    acc[p][j][rg] + bv;
        }
        __syncthreads();
        int lr = t >> 3, c0t = (t & 7) * 16;
        int gr = row0 + epi_row(p, lr);
        const float* src = &epi[lr * EPIW + c0t];
        const float* xsrc = x + (size_t)gr * DIMD + col0 + c0t;
        float* dst = out + (size_t)gr * DIMD + col0 + c0t;
        #pragma unroll
        for (int v = 0; v < 4; ++v) {
            float4 a = ((const float4*)src)[v];
            float4 xv = ((const float4*)xsrc)[v];
            a.x += xv.x; a.y += xv.y; a.z += xv.z; a.w += xv.w;
            ((float4*)dst)[v] = a;
        }
        __syncthreads();
    }
}

extern "C" void kernel_launch(void* const* d_in, const int* in_sizes, int n_in,
                              void* d_out, int out_size, void* d_ws, size_t ws_size,
                              hipStream_t stream) {
    const float* x     = (const float*)d_in[0];
    const float* ln_w  = (const float*)d_in[1];
    const float* ln_b  = (const float*)d_in[2];
    const float* Wh    = (const float*)d_in[3];
    const float* bh    = (const float*)d_in[4];
    const float* Wqk   = (const float*)d_in[5];
    const float* bqk   = (const float*)d_in[6];
    const float* gamma = (const float*)d_in[7];
    const float* beta  = (const float*)d_in[8];
    const float* Wo    = (const float*)d_in[9];
    const float* bo    = (const float*)d_in[10];
    float* out = (float*)d_out;

    // d_out (32 MiB) hosts short-lived buffers; all dead before gemm_final writes out.
    char* outb_ = (char*)d_out;
    bfraw* attn = (bfraw*)(outb_);                    //  8 MiB [64][256][256]
    bfraw* qq   = (bfraw*)(outb_ + 8388608);          //  4 MiB [16384][128]
    bfraw* kk   = (bfraw*)(outb_ + 12582912);         //  4 MiB
    bfraw* lq   = (bfraw*)(outb_ + 16777216);         //  4 MiB
    bfraw* WhT  = (bfraw*)(outb_ + 20971520);         //  2 MiB [2048][512]
    bfraw* WqkT = (bfraw*)(outb_ + 23068672);         //  128 KiB [128][512]

    // ws layout (byte offsets):
    char* wsb = (char*)d_ws;
    bfraw* vT      = (bfraw*)(wsb);                   // 32 MiB [64][1024][256]
    bfraw* gate    = (bfraw*)(wsb + 33554432);        // 32 MiB [16384][1024]
    bfraw* gated   = (bfraw*)(wsb + 67108864);        // 32 MiB [16384][1024]
    bfraw* normb   = (bfraw*)(wsb + 100663296);       // 16 MiB [16384][512]
    bfraw* kvT_raw = (bfraw*)(wsb + 117440512);       // 16 MiB [64][1024][128]
    bfraw* kvT_ex  = (bfraw*)(wsb + 134217728);       // 16 MiB [64][1024][128]
    bfraw* lkT     = (bfraw*)(wsb + 150994944);       //  4 MiB [64][128][256]
    bfraw* WoT     = (bfraw*)(wsb + 155189248);       //  1 MiB [512][1024]

    // 1. prep: LayerNorm + all weight transposes (one dispatch)
    prep_kernel<<<4096 + 1024 + 512 + 64, 256, 0, stream>>>(
        x, ln_w, ln_b, Wh, Wo, Wqk, normb, WhT, WoT, WqkT);
    // 2. merged h+qk GEMM (256^2, 16-wave pipelined engine): vT+gate+qq/lq/kk/lkT
    gemm_h256<<<576, 1024, 0, stream>>>(
        normb, WhT, WqkT, bh, bqk, gamma, beta, vT, gate, qq, lq, kk, lkT);
    // 3. fused kv + sim (one dispatch; kv blocks first)
    simkv_kernel<<<512 + 192, 256, 0, stream>>>(qq, kk, attn, vT, lkT, kvT_raw);
    // 4. exclusive cumsum over groups (with /G) -> kvT_ex
    cumsum2_kernel<<<(BATCH * QKD * HIDD) / 256, 256, 0, stream>>>(kvT_raw, kvT_ex);
    // 5. gated = gate .* (attn@vv + lq@kv_ex)
    quadlin_mfma<<<dim3(HIDD / 128, GRP / 128, BGRP), 256, 0, stream>>>(
        attn, vT, lq, kvT_ex, gate, gated);
    // 6. out = gated @ Wo + bo + x
    gemm_final<<<dim3(DIMD / 128, TROWS / 128), 256, 0, stream>>>(gated, WoT, bo, x, out);
}

// Round 4
// 270.234 us; speedup vs baseline: 1.2610x; 1.0098x over previous
//
#include <hip/hip_runtime.h>
#include <hip/hip_bf16.h>
#include <math.h>

// FLASH (GAU-style) fused block. Round 14: gemm_final rebuilt on the 16-wave
// 256-tile engine: 256x128 tiles -> exactly 256 blocks (1/CU, no round
// quantization), 3-slot LDS ring of 64-K super-steps (48KB/slot, 144KiB),
// uniform 3 gloads/thread/super-step, counted vmcnt(3), verified XOR-swizzle
// staging/reads, trivial bias+x epilogue. gemm_h256 and all else unchanged
// from R13 (272.9 us).
// b=4, n=4096, dim=512, hid=1024, qk=128, group=256.

#define BATCH 4
#define SEQ   4096
#define TROWS 16384      // BATCH*SEQ
#define DIMD  512
#define HIDD  1024
#define QKD   128
#define GRP   256
#define NGRP  16         // SEQ/GRP
#define BGRP  64         // BATCH*NGRP
#define EPIW  132        // padded LDS epilogue row stride (f32 path, 128-tiles)
#define EPB   130        // bf16 full-tile epilogue row stride (shorts)

typedef unsigned short bfraw;
typedef __attribute__((ext_vector_type(8))) short bf16x8;
typedef __attribute__((ext_vector_type(8))) unsigned short u16x8;
typedef __attribute__((ext_vector_type(4))) unsigned int u32x4;
typedef __attribute__((ext_vector_type(4))) float f32x4;

__device__ __forceinline__ float bf2f(bfraw u) {
    union { float f; unsigned int i; } c;
    c.i = ((unsigned int)u) << 16;
    return c.f;
}
__device__ __forceinline__ bfraw f2bf(float f) {
    unsigned int x = __float_as_uint(f);
    unsigned int r = (x + 0x7fffu + ((x >> 16) & 1u)) >> 16;   // RNE
    return (bfraw)r;
}
__device__ __forceinline__ unsigned int pkbf(float lo, float hi) {
    __hip_bfloat162 h2 = __float22bfloat162_rn(make_float2(lo, hi));
    union { __hip_bfloat162 h; unsigned int u; } c; c.h = h2;
    return c.u;
}
// 16 contiguous f32 -> 16 bf16 at dst (two 16B stores), packed cvt.
__device__ __forceinline__ void store16bf(bfraw* dst, const float* src) {
    u32x4 a, b;
    #pragma unroll
    for (int k = 0; k < 4; ++k) a[k] = pkbf(src[2 * k], src[2 * k + 1]);
    #pragma unroll
    for (int k = 0; k < 4; ++k) b[k] = pkbf(src[8 + 2 * k], src[8 + 2 * k + 1]);
    *(u32x4*)dst = a;
    *(u32x4*)(dst + 8) = b;
}
__device__ __forceinline__ float silu_f(float z) {
    return z / (1.f + __expf(-z));
}
__device__ __forceinline__ void gload_lds16(const void* g, void* l) {
    __builtin_amdgcn_global_load_lds(
        (const __attribute__((address_space(1))) unsigned int*)g,
        (__attribute__((address_space(3))) unsigned int*)l, 16, 0, 0);
}

// ===================== legacy 128^2 engine (other kernels) =====================
// One BK=32 MFMA step on staged tiles (4 waves, each 64x64 = 4x4 frags).
__device__ __forceinline__ void mfma_step(const bfraw* As, const bfraw* Bs,
                                          f32x4 acc[4][4], int wm, int wn,
                                          int q, int mi) {
    bf16x8 af[4], bfg[4];
    #pragma unroll
    for (int i = 0; i < 4; ++i)
        af[i] = *(const bf16x8*)&As[(size_t)(wm * 64 + i * 16 + mi) * 32 + q * 8];
    #pragma unroll
    for (int j = 0; j < 4; ++j)
        bfg[j] = *(const bf16x8*)&Bs[(size_t)(wn * 64 + j * 16 + mi) * 32 + q * 8];
    #pragma unroll
    for (int i = 0; i < 4; ++i)
        #pragma unroll
        for (int j = 0; j < 4; ++j)
            acc[i][j] = __builtin_amdgcn_mfma_f32_16x16x32_bf16(af[i], bfg[j], acc[i][j], 0, 0, 0);
}

// Double-buffered pipelined K-loop. 33280 bytes: 2x(A 8KB + B 8KB) + epi overlay.
#define SMEMP_DECL                                              \
    __shared__ __align__(16) char smem_[33280];                 \
    bfraw* A0buf = (bfraw*)smem_;                               \
    bfraw* B0buf = (bfraw*)(smem_ + 8192);                      \
    bfraw* A1buf = (bfraw*)(smem_ + 16384);                     \
    bfraw* B1buf = (bfraw*)(smem_ + 24576);

#define PIPE_DSTS                                               \
    bfraw* a0d  = A0buf + wid * 512;                            \
    bfraw* a0d2 = A0buf + 2048 + wid * 512;                     \
    bfraw* b0d  = B0buf + wid * 512;                            \
    bfraw* b0d2 = B0buf + 2048 + wid * 512;                     \
    bfraw* a1d  = A1buf + wid * 512;                            \
    bfraw* a1d2 = A1buf + 2048 + wid * 512;                     \
    bfraw* b1d  = B1buf + wid * 512;                            \
    bfraw* b1d2 = B1buf + 2048 + wid * 512;

#define KLOOP_PRE(Abase, Astr, Bbase, Bstr)                                    \
    const bfraw* pa0 = (Abase) + (size_t)(t >> 2) * (Astr) + (t & 3) * 8;      \
    const bfraw* pa1 = pa0 + (size_t)64 * (Astr);                              \
    const bfraw* pb0 = (Bbase) + (size_t)(t >> 2) * (Bstr) + (t & 3) * 8;      \
    const bfraw* pb1 = pb0 + (size_t)64 * (Bstr);

#define STAGE0                                                                 \
    do { gload_lds16(pa0, a0d); gload_lds16(pa1, a0d2);                        \
         gload_lds16(pb0, b0d); gload_lds16(pb1, b0d2);                        \
         pa0 += 32; pa1 += 32; pb0 += 32; pb1 += 32; } while (0)
#define STAGE1                                                                 \
    do { gload_lds16(pa0, a1d); gload_lds16(pa1, a1d2);                        \
         gload_lds16(pb0, b1d); gload_lds16(pb1, b1d2);                        \
         pa0 += 32; pa1 += 32; pb0 += 32; pb1 += 32; } while (0)

// NIT must be even (all call sites: K/32 ∈ {4,8,16,32}).
#define PIPE_LOOP(NIT, Abase, Astr, Bbase, Bstr)                               \
    {                                                                          \
        KLOOP_PRE(Abase, Astr, Bbase, Bstr)                                    \
        STAGE0;                                                                \
        for (int it = 0; it < (NIT); it += 2) {                                \
            __syncthreads();                                                   \
            if (it + 1 < (NIT)) STAGE1;                                        \
            mfma_step(A0buf, B0buf, acc, wm, wn, q, mi);                       \
            __syncthreads();                                                   \
            if (it + 2 < (NIT)) STAGE0;                                        \
            if (it + 1 < (NIT))                                                \
                mfma_step(A1buf, B1buf, acc, wm, wn, q, mi);                   \
        }                                                                      \
        __syncthreads();                                                       \
    }

__device__ __forceinline__ int epi_row(int p, int lr) {
    return (lr < 16) ? (p * 16 + lr) : (64 + p * 16 + (lr - 16));
}

// ------------- prep: ln (blocks 0..4095) + 3 weight transposes -------------
__global__ __launch_bounds__(256) void prep_kernel(const float* __restrict__ x,
                                                   const float* __restrict__ lnw,
                                                   const float* __restrict__ lnb,
                                                   const float* __restrict__ Wh,
                                                   const float* __restrict__ Wo,
                                                   const float* __restrict__ Wqk,
                                                   bfraw* __restrict__ normb,
                                                   bfraw* __restrict__ WhT,
                                                   bfraw* __restrict__ WoT,
                                                   bfraw* __restrict__ WqkT) {
    __shared__ float tile[32][33];
    int bid = blockIdx.x;
    int t = threadIdx.x;
    if (bid < 4096) {
        int row  = bid * 4 + (t >> 6);
        int lane = t & 63;
        const float* xr = x + (size_t)row * DIMD;
        float4 v0 = ((const float4*)xr)[lane];
        float4 v1 = ((const float4*)xr)[lane + 64];
        float s  = v0.x + v0.y + v0.z + v0.w + v1.x + v1.y + v1.z + v1.w;
        float ss = v0.x*v0.x + v0.y*v0.y + v0.z*v0.z + v0.w*v0.w
                 + v1.x*v1.x + v1.y*v1.y + v1.z*v1.z + v1.w*v1.w;
        #pragma unroll
        for (int off = 32; off; off >>= 1) {
            s  += __shfl_xor(s, off);
            ss += __shfl_xor(ss, off);
        }
        float mu  = s * (1.f / DIMD);
        float var = ss * (1.f / DIMD) - mu * mu;
        float inv = rsqrtf(var + 1e-5f);
        float4 w0 = ((const float4*)lnw)[lane],  w1 = ((const float4*)lnw)[lane + 64];
        float4 b0 = ((const float4*)lnb)[lane],  b1 = ((const float4*)lnb)[lane + 64];
        unsigned int o0 = pkbf((v0.x - mu) * inv * w0.x + b0.x,
                               (v0.y - mu) * inv * w0.y + b0.y);
        unsigned int o1 = pkbf((v0.z - mu) * inv * w0.z + b0.z,
                               (v0.w - mu) * inv * w0.w + b0.w);
        unsigned int o2 = pkbf((v1.x - mu) * inv * w1.x + b1.x,
                               (v1.y - mu) * inv * w1.y + b1.y);
        unsigned int o3 = pkbf((v1.z - mu) * inv * w1.z + b1.z,
                               (v1.w - mu) * inv * w1.w + b1.w);
        unsigned int* brow = (unsigned int*)(normb + (size_t)row * DIMD);
        ((uint2*)brow)[lane]      = make_uint2(o0, o1);
        ((uint2*)brow)[lane + 64] = make_uint2(o2, o3);
        return;
    }
    bid -= 4096;
    const float* in; bfraw* outp; int R, C, nx;
    if (bid < 1024)      { in = Wh;  outp = WhT;  R = DIMD; C = 2 * HIDD; nx = 64; }
    else if (bid < 1536) { bid -= 1024; in = Wo;  outp = WoT;  R = HIDD; C = DIMD; nx = 16; }
    else                 { bid -= 1536; in = Wqk; outp = WqkT; R = DIMD; C = QKD;  nx = 4; }
    int c0 = (bid % nx) * 32, r0 = (bid / nx) * 32;
    int tr = t >> 3, tc4 = (t & 7) * 4;
    float4 v = *(const float4*)&in[(size_t)(r0 + tr) * C + c0 + tc4];
    tile[tr][tc4 + 0] = v.x; tile[tr][tc4 + 1] = v.y;
    tile[tr][tc4 + 2] = v.z; tile[tr][tc4 + 3] = v.w;
    __syncthreads();
    ushort4 s;
    s.x = f2bf(tile[tc4 + 0][tr]);
    s.y = f2bf(tile[tc4 + 1][tr]);
    s.z = f2bf(tile[tc4 + 2][tr]);
    s.w = f2bf(tile[tc4 + 3][tr]);
    *(ushort4*)&outp[(size_t)(c0 + tr) * R + r0 + tc4] = s;
}

// ============ 256^2, 16-wave (1024-thr), 4-slot-ring h+qk GEMM ============
// Grid: 576 blocks (XCD-bijective swizzle -> (ct 0..8, by 0..63)), 1024 thr.
__global__ __launch_bounds__(1024, 4) void gemm_h256(
    const bfraw* __restrict__ A,      // normb [16384][512]
    const bfraw* __restrict__ WhT,    // [2048][512]
    const bfraw* __restrict__ WqkT,   // [128][512]
    const float* __restrict__ bh,     // [2048]
    const float* __restrict__ bqk,    // [128]
    const float* __restrict__ gamma,  // [4][128]
    const float* __restrict__ beta,   // [4][128]
    bfraw* __restrict__ vT,
    bfraw* __restrict__ gate,
    bfraw* __restrict__ qq,
    bfraw* __restrict__ lq,
    bfraw* __restrict__ kk,
    bfraw* __restrict__ lkT) {
    __shared__ __align__(16) char smem_[131072];
    const int t = threadIdx.x;
    const int lane = t & 63, wid = t >> 6;
    const int wm = wid >> 2, wn = wid & 3;       // 4 x 4 wave grid
    const int q = lane >> 4, mi = lane & 15;
    // XCD-bijective swizzle: 576 = 72*8; same-by column tiles stay on one XCD.
    int nid = (blockIdx.x & 7) * 72 + (blockIdx.x >> 3);
    const int ct = nid % 9, by = nid / 9;
    const int r0 = by * 256, c0 = ct * 256;

    const int lslot = (t & 7) ^ ((t >> 3) & 7);
    const int srow  = 2 * (t >> 3) + (lslot >> 2);      // 0..255
    const int skel  = (lslot & 3) * 8;
    const bfraw* Asrc = A + (size_t)(r0 + srow) * DIMD + skel;
    const bfraw* Bsrc;
    if (ct < 8) {
        Bsrc = WhT + (size_t)(c0 + srow) * DIMD + skel;
    } else {
        Bsrc = WqkT + (size_t)(srow & 127) * DIMD + skel;  // rows 128.. dup
    }
    const int swz = ((((mi & 1) << 2) | q) ^ ((mi >> 1) & 7)) << 4;
    const int a_off = (wm * 32 + (mi >> 1)) * 128 + swz;            // 64 rows/wm
    const int b_off = (wn * 32 + (mi >> 1)) * 128 + swz;

#define GH_STAGE(KT, SLOT)                                                    \
    do {                                                                      \
        char* sb_ = smem_ + (SLOT) * 32768;                                   \
        gload_lds16(Asrc + (KT) * 32, sb_ + t * 16);                          \
        gload_lds16(Bsrc + (KT) * 32, sb_ + 16384 + t * 16);                  \
    } while (0)

    f32x4 acc[4][4] = {};
    GH_STAGE(0, 0);
    GH_STAGE(1, 1);
    GH_STAGE(2, 2);
    asm volatile("s_waitcnt vmcnt(4)" ::: "memory");
    __builtin_amdgcn_s_barrier();

    #pragma unroll
    for (int j = 0; j < 16; ++j) {
        const char* cb = smem_ + (j & 3) * 32768;
        bf16x8 af[4], bfr[4];
        #pragma unroll
        for (int mf = 0; mf < 4; ++mf)
            af[mf] = *(const bf16x8*)(cb + a_off + mf * 1024);
        #pragma unroll
        for (int nf = 0; nf < 4; ++nf)
            bfr[nf] = *(const bf16x8*)(cb + 16384 + b_off + nf * 1024);
        if (j + 3 < 16) GH_STAGE(j + 3, (j + 3) & 3);
        __builtin_amdgcn_s_setprio(1);
        #pragma unroll
        for (int mf = 0; mf < 4; ++mf)
            #pragma unroll
            for (int nf = 0; nf < 4; ++nf)
                acc[mf][nf] = __builtin_amdgcn_mfma_f32_16x16x32_bf16(
                    af[mf], bfr[nf], acc[mf][nf], 0, 0, 0);
        __builtin_amdgcn_s_setprio(0);
        if (j + 3 < 16)      asm volatile("s_waitcnt vmcnt(4)" ::: "memory");
        else if (j + 2 < 16) asm volatile("s_waitcnt vmcnt(2)" ::: "memory");
        else if (j + 1 < 16) asm volatile("s_waitcnt vmcnt(0)" ::: "memory");
        __builtin_amdgcn_s_barrier();
    }
#undef GH_STAGE

    // ---- epilogue: 4 phases of 64 rows; phase p written by waves wm==p.
    float* epi = (float*)smem_;
    if (ct == 8) {
        float* gbl = (float*)(smem_ + 67584);    // gamma[512] | beta[512]
        if (t < 512) { gbl[t] = gamma[t]; gbl[t + 512] = beta[t]; }
        float bq4[4];
        #pragma unroll
        for (int nf = 0; nf < 4; ++nf)
            bq4[nf] = (wn < 2) ? bqk[wn * 64 + nf * 16 + mi] : 0.f;
        #pragma unroll
        for (int p = 0; p < 4; ++p) {
            if (wm == p && wn < 2) {
                #pragma unroll
                for (int mf = 0; mf < 4; ++mf)
                    #pragma unroll
                    for (int nf = 0; nf < 4; ++nf)
                        #pragma unroll
                        for (int rg = 0; rg < 4; ++rg)
                            epi[(mf * 16 + q * 4 + rg) * 132 + wn * 64 + nf * 16 + mi] =
                                silu_f(acc[mf][nf][rg] + bq4[nf]);
            }
            __syncthreads();
            if (t < 512) {   // heads 0..2: row-major [row][128]
                int lr = t >> 3, cs = (t & 7) * 16;
                float z[16];
                #pragma unroll
                for (int k = 0; k < 16; ++k) z[k] = epi[lr * 132 + cs + k];
                size_t growr = (size_t)(r0 + p * 64 + lr) * QKD + cs;
                #pragma unroll
                for (int hd = 0; hd < 3; ++hd) {
                    bfraw* arr = (hd == 0) ? qq : (hd == 1) ? lq : kk;
                    float tmp[16];
                    #pragma unroll
                    for (int k = 0; k < 16; ++k)
                        tmp[k] = z[k] * gbl[hd * 128 + cs + k] + gbl[512 + hd * 128 + cs + k];
                    store16bf(arr + growr, tmp);
                }
            } else {         // head 3 -> lkT[bg][c][256] (block-local transpose)
                int tt = t - 512;
                int c = tt >> 2, jh = (tt & 3) * 16;
                float g3 = gbl[384 + c], e3 = gbl[896 + c];
                float tmp[16];
                #pragma unroll
                for (int k = 0; k < 16; ++k)
                    tmp[k] = epi[(jh + k) * 132 + c] * g3 + e3;
                store16bf(lkT + ((size_t)by * QKD + c) * GRP + p * 64 + jh, tmp);
            }
            __syncthreads();
        }
        return;
    }
    float bias4[4];
    #pragma unroll
    for (int nf = 0; nf < 4; ++nf)
        bias4[nf] = bh[c0 + wn * 64 + nf * 16 + mi];
    if (ct < 4) {
        // v tile -> vT[bg][e][256] (block-local transpose). stride 257 (odd).
        #pragma unroll
        for (int p = 0; p < 4; ++p) {
            if (wm == p) {
                #pragma unroll
                for (int mf = 0; mf < 4; ++mf)
                    #pragma unroll
                    for (int nf = 0; nf < 4; ++nf)
                        #pragma unroll
                        for (int rg = 0; rg < 4; ++rg)
                            epi[(mf * 16 + q * 4 + rg) * 257 + wn * 64 + nf * 16 + mi] =
                                silu_f(acc[mf][nf][rg] + bias4[nf]);
            }
            __syncthreads();
            int e2 = t >> 2, js = (t & 3) * 16;
            float tmp[16];
            #pragma unroll
            for (int k = 0; k < 16; ++k)
                tmp[k] = epi[(js + k) * 257 + e2];
            store16bf(vT + ((size_t)by * HIDD + c0 + e2) * GRP + p * 64 + js, tmp);
            __syncthreads();
        }
    } else {
        // gate tile: row-major copy-out. stride 260 (16B-aligned rows).
        #pragma unroll
        for (int p = 0; p < 4; ++p) {
            if (wm == p) {
                #pragma unroll
                for (int mf = 0; mf < 4; ++mf)
                    #pragma unroll
                    for (int nf = 0; nf < 4; ++nf)
                        #pragma unroll
                        for (int rg = 0; rg < 4; ++rg)
                            epi[(mf * 16 + q * 4 + rg) * 260 + wn * 64 + nf * 16 + mi] =
                                silu_f(acc[mf][nf][rg] + bias4[nf]);
            }
            __syncthreads();
            int lr = t >> 4, cs = (t & 15) * 16;
            float tmp[16];
            #pragma unroll
            for (int k = 0; k < 16; ++k)
                tmp[k] = epi[lr * 260 + cs + k];
            store16bf(gate + (size_t)(r0 + p * 64 + lr) * HIDD + (c0 - HIDD) + cs, tmp);
            __syncthreads();
        }
    }
}

// ------------- fused sim + kv dispatch.
// blocks 0..511: kv; blocks 512..703: sim.
__global__ __launch_bounds__(256) void simkv_kernel(const bfraw* __restrict__ qq,
                                                    const bfraw* __restrict__ kk,
                                                    bfraw* __restrict__ attn,
                                                    const bfraw* __restrict__ vT,
                                                    const bfraw* __restrict__ lkT,
                                                    bfraw* __restrict__ kvT_raw) {
    SMEMP_DECL
    float* epi = (float*)smem_;
    int t = threadIdx.x;
    int lane = t & 63, wid = t >> 6;
    int wm = wid >> 1, wn = wid & 1;
    int q = lane >> 4, mi = lane & 15;
    int bid = blockIdx.x;
    f32x4 acc[4][4] = {};
    PIPE_DSTS
    if (bid < 512) {
        // ---- kv: kvT_raw[bg][e][d] = sum_j vT[bg][e][j] * lkT[bg][d][j] ----
        int bg = bid >> 3;
        int row0 = (bid & 7) * 128;
        PIPE_LOOP(8, vT + (size_t)bg * HIDD * GRP + (size_t)row0 * GRP, GRP,
                  lkT + (size_t)bg * QKD * GRP, GRP)
        bfraw* outg = kvT_raw + (size_t)bg * HIDD * QKD;
        #pragma unroll
        for (int p = 0; p < 4; ++p) {
            #pragma unroll
            for (int j = 0; j < 4; ++j)
                #pragma unroll
                for (int rg = 0; rg < 4; ++rg)
                    epi[(wm * 16 + q * 4 + rg) * EPIW + wn * 64 + j * 16 + mi] = acc[p][j][rg];
            __syncthreads();
            int lr = t >> 3, c0t = (t & 7) * 16;
            int gr = row0 + epi_row(p, lr);
            store16bf(outg + (size_t)gr * QKD + c0t, &epi[lr * EPIW + c0t]);
            __syncthreads();
        }
        return;
    }
    // ---- sim: attn[bg][i][j] = mask * relu(qq_i . kk_j / G)^2 ----
    int i = bid - 512;
    int bg = i & 63;
    int tid = i >> 6;
    int ry = (tid == 0) ? 0 : 1;
    int rx = (tid == 2) ? 1 : 0;
    int row0 = ry * 128, col0 = rx * 128;
    PIPE_LOOP(4, qq + (size_t)(bg * GRP + row0) * QKD, QKD,
              kk + (size_t)(bg * GRP + col0) * QKD, QKD)
    bfraw* ag = attn + (size_t)bg * GRP * GRP;
    #pragma unroll
    for (int p = 0; p < 4; ++p) {
        #pragma unroll
        for (int j = 0; j < 4; ++j) {
            int colg = col0 + wn * 64 + j * 16 + mi;
            #pragma unroll
            for (int rg = 0; rg < 4; ++rg) {
                int rowg = row0 + wm * 64 + p * 16 + q * 4 + rg;
                float s = acc[p][j][rg] * (1.f / GRP);
                s = fmaxf(s, 0.f);
                s = s * s;
                epi[(wm * 16 + q * 4 + rg) * EPIW + wn * 64 + j * 16 + mi] =
                    (colg > rowg) ? 0.f : s;
            }
        }
        __syncthreads();
        int lr = t >> 3, c0t = (t & 7) * 16;
        int gr = row0 + epi_row(p, lr);
        store16bf(ag + (size_t)gr * GRP + col0 + c0t, &epi[lr * EPIW + c0t]);
        __syncthreads();
    }
}

// ------------- exclusive cumsum over groups (with /G) -------------
__global__ __launch_bounds__(256) void cumsum2_kernel(const bfraw* __restrict__ raw,
                                                      bfraw* __restrict__ ex) {
    int idx = blockIdx.x * 256 + threadIdx.x;
    int b = idx >> 17;
    int r = idx & 131071;
    const bfraw* rp = raw + (size_t)b * NGRP * 131072 + r;
    bfraw* ep = ex + (size_t)b * NGRP * 131072 + r;
    float run = 0.f;
    #pragma unroll
    for (int g = 0; g < NGRP; ++g) {
        ep[(size_t)g * 131072] = f2bf(run);
        run += bf2f(rp[(size_t)g * 131072]) * (1.f / GRP);
    }
}

// ------------- gated = gate .* (attn@vv + lq@kv_ex)  (bf16 out) -------------
__global__ __launch_bounds__(256) void quadlin_mfma(const bfraw* __restrict__ attn,
                                                    const bfraw* __restrict__ vT,
                                                    const bfraw* __restrict__ lq,
                                                    const bfraw* __restrict__ kvT_ex,
                                                    const bfraw* __restrict__ gate,
                                                    bfraw* __restrict__ gated) {
    int bg = blockIdx.z;
    int row0 = blockIdx.y * 128;
    int col0 = blockIdx.x * 128;
    SMEMP_DECL
    float* epi = (float*)smem_;
    int t = threadIdx.x;
    int lane = t & 63, wid = t >> 6;
    int wm = wid >> 1, wn = wid & 1;
    int q = lane >> 4, mi = lane & 15;
    f32x4 acc[4][4] = {};
    PIPE_DSTS
    // Part 1: quadratic. A = attn rows (stride 256), BT = vT rows (stride 256).
    {
        int nit = (row0 + 128) >> 5;     // causal: attn[i][j]=0 for j>i
        PIPE_LOOP(nit, attn + (size_t)bg * GRP * GRP + (size_t)row0 * GRP, GRP,
                  vT + (size_t)bg * HIDD * GRP + (size_t)col0 * GRP, GRP)
    }
    // Part 2: linear. A = lq rows (stride 128), BT = kvT_ex rows (stride 128).
    PIPE_LOOP(4, lq + (size_t)(bg * GRP + row0) * QKD, QKD,
              kvT_ex + (size_t)bg * HIDD * QKD + (size_t)col0 * QKD, QKD)
    #pragma unroll
    for (int p = 0; p < 4; ++p) {
        #pragma unroll
        for (int j = 0; j < 4; ++j)
            #pragma unroll
            for (int rg = 0; rg < 4; ++rg)
                epi[(wm * 16 + q * 4 + rg) * EPIW + wn * 64 + j * 16 + mi] = acc[p][j][rg];
        __syncthreads();
        int lr = t >> 3, c0t = (t & 7) * 16;
        int gr = row0 + epi_row(p, lr);          // group-local row
        size_t grow = (size_t)bg * GRP + gr;
        const float* src = &epi[lr * EPIW + c0t];
        const bfraw* gsrc = gate + grow * HIDD + col0 + c0t;
        u16x8 g0 = *(const u16x8*)gsrc;
        u16x8 g1 = *(const u16x8*)(gsrc + 8);
        float tmp[16];
        #pragma unroll
        for (int k = 0; k < 8; ++k) tmp[k] = src[k] * bf2f(g0[k]);
        #pragma unroll
        for (int k = 0; k < 8; ++k) tmp[8 + k] = src[8 + k] * bf2f(g1[k]);
        store16bf(gated + grow * HIDD + col0 + c0t, tmp);
        __syncthreads();
    }
}

// ======= final: out = gated @ WoT^T + bo + x (16-wave 256x128 engine) =======
// Grid: exactly 256 blocks (1/CU), 1024 thr, 16 waves as 4M x 4N, per-wave
// 64 rows x 32 cols (acc[4][2]). 3-slot ring of 64-K super-steps: slot =
// A 32KB (2 halves, swizzled) + B 16KB = 48KB; 144 KiB LDS. 3 uniform
// gloads/thread/super-step, counted vmcnt(3) (never 0 until tail).
__global__ __launch_bounds__(1024, 4) void gemm_final(
    const bfraw* __restrict__ A,      // gated [16384][1024]
    const bfraw* __restrict__ BT,     // WoT [512][1024]
    const float* __restrict__ bo,     // [512]
    const float* __restrict__ x,      // [16384][512]
    float* __restrict__ out) {        // [16384][512]
    __shared__ __align__(16) char smem_[147456];
    const int t = threadIdx.x;
    const int lane = t & 63, wid = t >> 6;
    const int wm = wid >> 2, wn = wid & 3;       // 4M x 4N
    const int q = lane >> 4, mi = lane & 15;
    // XCD swizzle: 256 = 32*8; 4 col-blocks of one row-tile share an XCD.
    int nid = (blockIdx.x & 7) * 32 + (blockIdx.x >> 3);
    const int by = nid >> 2, cx = nid & 3;
    const int r0 = by * 256, c0 = cx * 128;

    // staging: A half c (k 32c..32c+31) = 128 lines x 128B at slot + c*16K.
    const int lslot = (t & 7) ^ ((t >> 3) & 7);
    const int a_row = 2 * (t >> 3) + (lslot >> 2);       // 0..255
    const int a_kel = (lslot & 3) * 8;
    const bfraw* Asrc = A + (size_t)(r0 + a_row) * HIDD + a_kel;
    // B: 16KB both halves; thread t covers byte t*16; t>=512 -> half 1.
    const int u = t & 511;
    const int lsb = (u & 7) ^ ((u >> 3) & 7);
    const int b_row = 2 * (u >> 3) + (lsb >> 2);         // 0..127
    const int b_kel = (lsb & 3) * 8 + (t >> 9) * 32;
    const bfraw* Bsrc = BT + (size_t)(c0 + b_row) * HIDD + b_kel;

    const int swz = ((((mi & 1) << 2) | q) ^ ((mi >> 1) & 7)) << 4;
    const int a_off = (wm * 32 + (mi >> 1)) * 128 + swz;   // 64 rows/wave
    const int b_off = (wn * 16 + (mi >> 1)) * 128 + swz;   // 32 cols/wave

#define GF_STAGE(SS, SLOT)                                                    \
    do {                                                                      \
        char* sb_ = smem_ + (SLOT) * 49152;                                   \
        gload_lds16(Asrc + (SS) * 64,      sb_ + t * 16);                     \
        gload_lds16(Asrc + (SS) * 64 + 32, sb_ + 16384 + t * 16);             \
        gload_lds16(Bsrc + (SS) * 64,      sb_ + 32768 + t * 16);             \
    } while (0)

    f32x4 acc[4][2] = {};
    GF_STAGE(0, 0);
    GF_STAGE(1, 1);
    asm volatile("s_waitcnt vmcnt(3)" ::: "memory");
    __builtin_amdgcn_s_barrier();

    #pragma unroll
    for (int ss = 0; ss < 16; ++ss) {
        if (ss + 2 < 16) GF_STAGE(ss + 2, (ss + 2) % 3);
        const char* cb = smem_ + (ss % 3) * 49152;
        #pragma unroll
        for (int h = 0; h < 2; ++h) {
            bf16x8 af[4], bfr[2];
            #pragma unroll
            for (int mf = 0; mf < 4; ++mf)
                af[mf] = *(const bf16x8*)(cb + h * 16384 + a_off + mf * 1024);
            #pragma unroll
            for (int nf = 0; nf < 2; ++nf)
                bfr[nf] = *(const bf16x8*)(cb + 32768 + h * 8192 + b_off + nf * 1024);
            __builtin_amdgcn_s_setprio(1);
            #pragma unroll
            for (int mf = 0; mf < 4; ++mf)
                #pragma unroll
                for (int nf = 0; nf < 2; ++nf)
                    acc[mf][nf] = __builtin_amdgcn_mfma_f32_16x16x32_bf16(
                        af[mf], bfr[nf], acc[mf][nf], 0, 0, 0);
            __builtin_amdgcn_s_setprio(0);
        }
        if (ss + 2 < 16)      asm volatile("s_waitcnt vmcnt(3)" ::: "memory");
        else if (ss + 1 < 16) asm volatile("s_waitcnt vmcnt(0)" ::: "memory");
        __builtin_amdgcn_s_barrier();
    }
#undef GF_STAGE

    // epilogue: 4 phases of 64 rows (phase p = waves wm==p); bias + x add.
    float* epi = (float*)smem_;
    float bo2[2];
    #pragma unroll
    for (int nf = 0; nf < 2; ++nf)
        bo2[nf] = bo[c0 + wn * 32 + nf * 16 + mi];
    #pragma unroll
    for (int p = 0; p < 4; ++p) {
        if (wm == p) {
            #pragma unroll
            for (int mf = 0; mf < 4; ++mf)
                #pragma unroll
                for (int nf = 0; nf < 2; ++nf)
                    #pragma unroll
                    for (int rg = 0; rg < 4; ++rg)
                        epi[(mf * 16 + q * 4 + rg) * 132 + wn * 32 + nf * 16 + mi] =
                            acc[mf][nf][rg] + bo2[nf];
        }
        __syncthreads();
        int lr = t >> 4, cs = (t & 15) * 8;
        const float* src = epi + lr * 132 + cs;
        const float* xs = x + (size_t)(r0 + p * 64 + lr) * DIMD + c0 + cs;
        float* dst = out + (size_t)(r0 + p * 64 + lr) * DIMD + c0 + cs;
        #pragma unroll
        for (int v = 0; v < 2; ++v) {
            float4 a = ((const float4*)src)[v];
            float4 xv = ((const float4*)xs)[v];
            a.x += xv.x; a.y += xv.y; a.z += xv.z; a.w += xv.w;
            ((float4*)dst)[v] = a;
        }
        __syncthreads();
    }
}

extern "C" void kernel_launch(void* const* d_in, const int* in_sizes, int n_in,
                              void* d_out, int out_size, void* d_ws, size_t ws_size,
                              hipStream_t stream) {
    const float* x     = (const float*)d_in[0];
    const float* ln_w  = (const float*)d_in[1];
    const float* ln_b  = (const float*)d_in[2];
    const float* Wh    = (const float*)d_in[3];
    const float* bh    = (const float*)d_in[4];
    const float* Wqk   = (const float*)d_in[5];
    const float* bqk   = (const float*)d_in[6];
    const float* gamma = (const float*)d_in[7];
    const float* beta  = (const float*)d_in[8];
    const float* Wo    = (const float*)d_in[9];
    const float* bo    = (const float*)d_in[10];
    float* out = (float*)d_out;

    // d_out (32 MiB) hosts short-lived buffers; all dead before gemm_final writes out.
    char* outb_ = (char*)d_out;
    bfraw* attn = (bfraw*)(outb_);                    //  8 MiB [64][256][256]
    bfraw* qq   = (bfraw*)(outb_ + 8388608);          //  4 MiB [16384][128]
    bfraw* kk   = (bfraw*)(outb_ + 12582912);         //  4 MiB
    bfraw* lq   = (bfraw*)(outb_ + 16777216);         //  4 MiB
    bfraw* WhT  = (bfraw*)(outb_ + 20971520);         //  2 MiB [2048][512]
    bfraw* WqkT = (bfraw*)(outb_ + 23068672);         //  128 KiB [128][512]

    // ws layout (byte offsets):
    char* wsb = (char*)d_ws;
    bfraw* vT      = (bfraw*)(wsb);                   // 32 MiB [64][1024][256]
    bfraw* gate    = (bfraw*)(wsb + 33554432);        // 32 MiB [16384][1024]
    bfraw* gated   = (bfraw*)(wsb + 67108864);        // 32 MiB [16384][1024]
    bfraw* normb   = (bfraw*)(wsb + 100663296);       // 16 MiB [16384][512]
    bfraw* kvT_raw = (bfraw*)(wsb + 117440512);       // 16 MiB [64][1024][128]
    bfraw* kvT_ex  = (bfraw*)(wsb + 134217728);       // 16 MiB [64][1024][128]
    bfraw* lkT     = (bfraw*)(wsb + 150994944);       //  4 MiB [64][128][256]
    bfraw* WoT     = (bfraw*)(wsb + 155189248);       //  1 MiB [512][1024]

    // 1. prep: LayerNorm + all weight transposes (one dispatch)
    prep_kernel<<<4096 + 1024 + 512 + 64, 256, 0, stream>>>(
        x, ln_w, ln_b, Wh, Wo, Wqk, normb, WhT, WoT, WqkT);
    // 2. merged h+qk GEMM (256^2, 16-wave pipelined engine): vT+gate+qq/lq/kk/lkT
    gemm_h256<<<576, 1024, 0, stream>>>(
        normb, WhT, WqkT, bh, bqk, gamma, beta, vT, gate, qq, lq, kk, lkT);
    // 3. fused kv + sim (one dispatch; kv blocks first)
    simkv_kernel<<<512 + 192, 256, 0, stream>>>(qq, kk, attn, vT, lkT, kvT_raw);
    // 4. exclusive cumsum over groups (with /G) -> kvT_ex
    cumsum2_kernel<<<(BATCH * QKD * HIDD) / 256, 256, 0, stream>>>(kvT_raw, kvT_ex);
    // 5. gated = gate .* (attn@vv + lq@kv_ex)
    quadlin_mfma<<<dim3(HIDD / 128, GRP / 128, BGRP), 256, 0, stream>>>(
        attn, vT, lq, kvT_ex, gate, gated);
    // 6. out = gated @ Wo + bo + x  (16-wave 256x128 engine, 256 blocks)
    gemm_final<<<256, 1024, 0, stream>>>(gated, WoT, bo, x, out);
}

// Round 6
// 257.719 us; speedup vs baseline: 1.3222x; 1.0486x over previous
//
#include <hip/hip_runtime.h>
#include <hip/hip_bf16.h>
#include <math.h>

// FLASH (GAU-style) fused block. Round 16: fixes R15's LDS staging race.
// gemm_h256: 128x256 tiles, 512 thr / 8 waves, now a 3-slot LDS ring with
// depth-2 prefetch (R14 gemm_final's verified pattern): stage(j+2) at iter j,
// counted vmcnt(3) BEFORE the barrier guarantees stage(j+1) landed for every
// wave; reads happen after the barrier (collective guarantee restored).
// LDS 72KB -> still 2 blocks/CU co-resident. All else unchanged from R15.
// b=4, n=4096, dim=512, hid=1024, qk=128, group=256.

#define BATCH 4
#define SEQ   4096
#define TROWS 16384      // BATCH*SEQ
#define DIMD  512
#define HIDD  1024
#define QKD   128
#define GRP   256
#define NGRP  16         // SEQ/GRP
#define BGRP  64         // BATCH*NGRP
#define EPIW  132        // padded LDS epilogue row stride (f32 path, 128-tiles)
#define EPB   130        // bf16 full-tile epilogue row stride (shorts)

typedef unsigned short bfraw;
typedef __attribute__((ext_vector_type(8))) short bf16x8;
typedef __attribute__((ext_vector_type(8))) unsigned short u16x8;
typedef __attribute__((ext_vector_type(4))) unsigned int u32x4;
typedef __attribute__((ext_vector_type(4))) float f32x4;

__device__ __forceinline__ float bf2f(bfraw u) {
    union { float f; unsigned int i; } c;
    c.i = ((unsigned int)u) << 16;
    return c.f;
}
__device__ __forceinline__ bfraw f2bf(float f) {
    unsigned int x = __float_as_uint(f);
    unsigned int r = (x + 0x7fffu + ((x >> 16) & 1u)) >> 16;   // RNE
    return (bfraw)r;
}
__device__ __forceinline__ unsigned int pkbf(float lo, float hi) {
    __hip_bfloat162 h2 = __float22bfloat162_rn(make_float2(lo, hi));
    union { __hip_bfloat162 h; unsigned int u; } c; c.h = h2;
    return c.u;
}
// 16 contiguous f32 -> 16 bf16 at dst (two 16B stores), packed cvt.
__device__ __forceinline__ void store16bf(bfraw* dst, const float* src) {
    u32x4 a, b;
    #pragma unroll
    for (int k = 0; k < 4; ++k) a[k] = pkbf(src[2 * k], src[2 * k + 1]);
    #pragma unroll
    for (int k = 0; k < 4; ++k) b[k] = pkbf(src[8 + 2 * k], src[8 + 2 * k + 1]);
    *(u32x4*)dst = a;
    *(u32x4*)(dst + 8) = b;
}
// 8 contiguous f32 -> 8 bf16 at dst (one 16B store).
__device__ __forceinline__ void store8bf(bfraw* dst, const float* src) {
    u32x4 a;
    #pragma unroll
    for (int k = 0; k < 4; ++k) a[k] = pkbf(src[2 * k], src[2 * k + 1]);
    *(u32x4*)dst = a;
}
__device__ __forceinline__ float silu_f(float z) {
    return z / (1.f + __expf(-z));
}
__device__ __forceinline__ void gload_lds16(const void* g, void* l) {
    __builtin_amdgcn_global_load_lds(
        (const __attribute__((address_space(1))) unsigned int*)g,
        (__attribute__((address_space(3))) unsigned int*)l, 16, 0, 0);
}

// ===================== legacy 128^2 engine (other kernels) =====================
// One BK=32 MFMA step on staged tiles (4 waves, each 64x64 = 4x4 frags).
__device__ __forceinline__ void mfma_step(const bfraw* As, const bfraw* Bs,
                                          f32x4 acc[4][4], int wm, int wn,
                                          int q, int mi) {
    bf16x8 af[4], bfg[4];
    #pragma unroll
    for (int i = 0; i < 4; ++i)
        af[i] = *(const bf16x8*)&As[(size_t)(wm * 64 + i * 16 + mi) * 32 + q * 8];
    #pragma unroll
    for (int j = 0; j < 4; ++j)
        bfg[j] = *(const bf16x8*)&Bs[(size_t)(wn * 64 + j * 16 + mi) * 32 + q * 8];
    #pragma unroll
    for (int i = 0; i < 4; ++i)
        #pragma unroll
        for (int j = 0; j < 4; ++j)
            acc[i][j] = __builtin_amdgcn_mfma_f32_16x16x32_bf16(af[i], bfg[j], acc[i][j], 0, 0, 0);
}

// Double-buffered pipelined K-loop. 33280 bytes: 2x(A 8KB + B 8KB) + epi overlay.
#define SMEMP_DECL                                              \
    __shared__ __align__(16) char smem_[33280];                 \
    bfraw* A0buf = (bfraw*)smem_;                               \
    bfraw* B0buf = (bfraw*)(smem_ + 8192);                      \
    bfraw* A1buf = (bfraw*)(smem_ + 16384);                     \
    bfraw* B1buf = (bfraw*)(smem_ + 24576);

#define PIPE_DSTS                                               \
    bfraw* a0d  = A0buf + wid * 512;                            \
    bfraw* a0d2 = A0buf + 2048 + wid * 512;                     \
    bfraw* b0d  = B0buf + wid * 512;                            \
    bfraw* b0d2 = B0buf + 2048 + wid * 512;                     \
    bfraw* a1d  = A1buf + wid * 512;                            \
    bfraw* a1d2 = A1buf + 2048 + wid * 512;                     \
    bfraw* b1d  = B1buf + wid * 512;                            \
    bfraw* b1d2 = B1buf + 2048 + wid * 512;

#define KLOOP_PRE(Abase, Astr, Bbase, Bstr)                                    \
    const bfraw* pa0 = (Abase) + (size_t)(t >> 2) * (Astr) + (t & 3) * 8;      \
    const bfraw* pa1 = pa0 + (size_t)64 * (Astr);                              \
    const bfraw* pb0 = (Bbase) + (size_t)(t >> 2) * (Bstr) + (t & 3) * 8;      \
    const bfraw* pb1 = pb0 + (size_t)64 * (Bstr);

#define STAGE0                                                                 \
    do { gload_lds16(pa0, a0d); gload_lds16(pa1, a0d2);                        \
         gload_lds16(pb0, b0d); gload_lds16(pb1, b0d2);                        \
         pa0 += 32; pa1 += 32; pb0 += 32; pb1 += 32; } while (0)
#define STAGE1                                                                 \
    do { gload_lds16(pa0, a1d); gload_lds16(pa1, a1d2);                        \
         gload_lds16(pb0, b1d); gload_lds16(pb1, b1d2);                        \
         pa0 += 32; pa1 += 32; pb0 += 32; pb1 += 32; } while (0)

// NIT must be even (all call sites: K/32 ∈ {4,8,16,32}).
#define PIPE_LOOP(NIT, Abase, Astr, Bbase, Bstr)                               \
    {                                                                          \
        KLOOP_PRE(Abase, Astr, Bbase, Bstr)                                    \
        STAGE0;                                                                \
        for (int it = 0; it < (NIT); it += 2) {                                \
            __syncthreads();                                                   \
            if (it + 1 < (NIT)) STAGE1;                                        \
            mfma_step(A0buf, B0buf, acc, wm, wn, q, mi);                       \
            __syncthreads();                                                   \
            if (it + 2 < (NIT)) STAGE0;                                        \
            if (it + 1 < (NIT))                                                \
                mfma_step(A1buf, B1buf, acc, wm, wn, q, mi);                   \
        }                                                                      \
        __syncthreads();                                                       \
    }

__device__ __forceinline__ int epi_row(int p, int lr) {
    return (lr < 16) ? (p * 16 + lr) : (64 + p * 16 + (lr - 16));
}

// ------------- prep: ln (blocks 0..4095) + 3 weight transposes -------------
__global__ __launch_bounds__(256) void prep_kernel(const float* __restrict__ x,
                                                   const float* __restrict__ lnw,
                                                   const float* __restrict__ lnb,
                                                   const float* __restrict__ Wh,
                                                   const float* __restrict__ Wo,
                                                   const float* __restrict__ Wqk,
                                                   bfraw* __restrict__ normb,
                                                   bfraw* __restrict__ WhT,
                                                   bfraw* __restrict__ WoT,
                                                   bfraw* __restrict__ WqkT) {
    __shared__ float tile[32][33];
    int bid = blockIdx.x;
    int t = threadIdx.x;
    if (bid < 4096) {
        int row  = bid * 4 + (t >> 6);
        int lane = t & 63;
        const float* xr = x + (size_t)row * DIMD;
        float4 v0 = ((const float4*)xr)[lane];
        float4 v1 = ((const float4*)xr)[lane + 64];
        float s  = v0.x + v0.y + v0.z + v0.w + v1.x + v1.y + v1.z + v1.w;
        float ss = v0.x*v0.x + v0.y*v0.y + v0.z*v0.z + v0.w*v0.w
                 + v1.x*v1.x + v1.y*v1.y + v1.z*v1.z + v1.w*v1.w;
        #pragma unroll
        for (int off = 32; off; off >>= 1) {
            s  += __shfl_xor(s, off);
            ss += __shfl_xor(ss, off);
        }
        float mu  = s * (1.f / DIMD);
        float var = ss * (1.f / DIMD) - mu * mu;
        float inv = rsqrtf(var + 1e-5f);
        float4 w0 = ((const float4*)lnw)[lane],  w1 = ((const float4*)lnw)[lane + 64];
        float4 b0 = ((const float4*)lnb)[lane],  b1 = ((const float4*)lnb)[lane + 64];
        unsigned int o0 = pkbf((v0.x - mu) * inv * w0.x + b0.x,
                               (v0.y - mu) * inv * w0.y + b0.y);
        unsigned int o1 = pkbf((v0.z - mu) * inv * w0.z + b0.z,
                               (v0.w - mu) * inv * w0.w + b0.w);
        unsigned int o2 = pkbf((v1.x - mu) * inv * w1.x + b1.x,
                               (v1.y - mu) * inv * w1.y + b1.y);
        unsigned int o3 = pkbf((v1.z - mu) * inv * w1.z + b1.z,
                               (v1.w - mu) * inv * w1.w + b1.w);
        unsigned int* brow = (unsigned int*)(normb + (size_t)row * DIMD);
        ((uint2*)brow)[lane]      = make_uint2(o0, o1);
        ((uint2*)brow)[lane + 64] = make_uint2(o2, o3);
        return;
    }
    bid -= 4096;
    const float* in; bfraw* outp; int R, C, nx;
    if (bid < 1024)      { in = Wh;  outp = WhT;  R = DIMD; C = 2 * HIDD; nx = 64; }
    else if (bid < 1536) { bid -= 1024; in = Wo;  outp = WoT;  R = HIDD; C = DIMD; nx = 16; }
    else                 { bid -= 1536; in = Wqk; outp = WqkT; R = DIMD; C = QKD;  nx = 4; }
    int c0 = (bid % nx) * 32, r0 = (bid / nx) * 32;
    int tr = t >> 3, tc4 = (t & 7) * 4;
    float4 v = *(const float4*)&in[(size_t)(r0 + tr) * C + c0 + tc4];
    tile[tr][tc4 + 0] = v.x; tile[tr][tc4 + 1] = v.y;
    tile[tr][tc4 + 2] = v.z; tile[tr][tc4 + 3] = v.w;
    __syncthreads();
    ushort4 s;
    s.x = f2bf(tile[tc4 + 0][tr]);
    s.y = f2bf(tile[tc4 + 1][tr]);
    s.z = f2bf(tile[tc4 + 2][tr]);
    s.w = f2bf(tile[tc4 + 3][tr]);
    *(ushort4*)&outp[(size_t)(c0 + tr) * R + r0 + tc4] = s;
}

// ========== 128x256-tile, 8-wave (512-thr), 3-slot-ring h+qk GEMM ==========
// Grid: 1152 blocks (XCD swizzle: (ct 0..8, by 0..127)), 512 thr.
// LDS: 3 slots x (A 8K + B 16K) = 72 KiB -> 2 blocks/CU co-resident.
// Depth-2 prefetch (R14-verified pattern): stage(j+2) at iter j; vmcnt(3)
// before the end barrier guarantees stage(j+1) landed for every wave;
// reads strictly after the barrier.
__global__ __launch_bounds__(512, 4) void gemm_h256(
    const bfraw* __restrict__ A,      // normb [16384][512]
    const bfraw* __restrict__ WhT,    // [2048][512]
    const bfraw* __restrict__ WqkT,   // [128][512]
    const float* __restrict__ bh,     // [2048]
    const float* __restrict__ bqk,    // [128]
    const float* __restrict__ gamma,  // [4][128]
    const float* __restrict__ beta,   // [4][128]
    bfraw* __restrict__ vT,
    bfraw* __restrict__ gate,
    bfraw* __restrict__ qq,
    bfraw* __restrict__ lq,
    bfraw* __restrict__ kk,
    bfraw* __restrict__ lkT) {
    __shared__ __align__(16) char smem_[73728];
    const int t = threadIdx.x;
    const int lane = t & 63, wid = t >> 6;
    const int wm = wid >> 2, wn = wid & 3;       // 2M x 4N wave grid
    const int q = lane >> 4, mi = lane & 15;
    // XCD swizzle: 1152 = 8*144; per XCD: 16 by-strips x their 9 ct tiles.
    int nid = (blockIdx.x & 7) * 144 + (blockIdx.x >> 3);
    const int ct = nid % 9, by = nid / 9;        // by 0..127
    const int r0 = by * 128, c0 = ct * 256;
    const int bg = r0 >> 8;                      // group index
    const int jb0 = r0 & 255;                    // row offset within group

    // staging: pre-swizzled global sources, linear LDS dests.
    // A region 8KB = 64 lines x 128B (128 rows); B region 16KB (256 rows,
    // two 128-row halves staged separately).
    const int lslot = (t & 7) ^ ((t >> 3) & 7);
    const int srow  = 2 * (t >> 3) + (lslot >> 2);      // 0..127
    const int skel  = (lslot & 3) * 8;
    const bfraw* Asrc = A + (size_t)(r0 + srow) * DIMD + skel;
    const bfraw* Bsrc0;
    const bfraw* Bsrc1;
    if (ct < 8) {
        Bsrc0 = WhT + (size_t)(c0 + srow) * DIMD + skel;
        Bsrc1 = Bsrc0 + (size_t)128 * DIMD;
    } else {
        Bsrc0 = WqkT + (size_t)srow * DIMD + skel;   // rows 0..127 real
        Bsrc1 = Bsrc0;                               // cols 128..255 garbage dup
    }
    // swizzled LDS read offsets (verified involution).
    const int swz = ((((mi & 1) << 2) | q) ^ ((mi >> 1) & 7)) << 4;
    const int a_off = (wm * 32 + (mi >> 1)) * 128 + swz;   // 64 rows/wave
    const int b_off = (wn * 32 + (mi >> 1)) * 128 + swz;   // 64 cols/wave

#define GH_STAGE(KT, SLOT)                                                    \
    do {                                                                      \
        char* sb_ = smem_ + (SLOT) * 24576;                                   \
        gload_lds16(Asrc  + (KT) * 32, sb_ + t * 16);                         \
        gload_lds16(Bsrc0 + (KT) * 32, sb_ + 8192 + t * 16);                  \
        gload_lds16(Bsrc1 + (KT) * 32, sb_ + 16384 + t * 16);                 \
    } while (0)

    f32x4 acc[4][4] = {};
    GH_STAGE(0, 0);
    GH_STAGE(1, 1);
    asm volatile("s_waitcnt vmcnt(3)" ::: "memory");   // stage(0) landed
    __builtin_amdgcn_s_barrier();

    #pragma unroll
    for (int j = 0; j < 16; ++j) {
        if (j + 2 < 16) GH_STAGE(j + 2, (j + 2) % 3);
        const char* cb = smem_ + (j % 3) * 24576;
        bf16x8 af[4], bfr[4];
        #pragma unroll
        for (int mf = 0; mf < 4; ++mf)
            af[mf] = *(const bf16x8*)(cb + a_off + mf * 1024);
        #pragma unroll
        for (int nf = 0; nf < 4; ++nf)
            bfr[nf] = *(const bf16x8*)(cb + 8192 + b_off + nf * 1024);
        __builtin_amdgcn_s_setprio(1);
        #pragma unroll
        for (int mf = 0; mf < 4; ++mf)
            #pragma unroll
            for (int nf = 0; nf < 4; ++nf)
                acc[mf][nf] = __builtin_amdgcn_mfma_f32_16x16x32_bf16(
                    af[mf], bfr[nf], acc[mf][nf], 0, 0, 0);
        __builtin_amdgcn_s_setprio(0);
        if (j + 2 < 16)      asm volatile("s_waitcnt vmcnt(3)" ::: "memory");
        else if (j + 1 < 16) asm volatile("s_waitcnt vmcnt(0)" ::: "memory");
        __builtin_amdgcn_s_barrier();
    }
#undef GH_STAGE

    // ---- epilogue: 4 phases of 32 rows. Phase p2: waves wm == p2>>1 hold
    //      the rows; mf = (p2&1)*2 + mf2, local row = mf2*16 + q*4 + rg,
    //      col = wn*64 + nf*16 + mi.
    float* epi = (float*)smem_;
    if (ct == 8) {
        // qk tile: cols 0..127 (wn<2) real. stride 132 (f32).
        float* gbl = (float*)(smem_ + 36864);    // gamma[512] | beta[512]
        gbl[t] = gamma[t];
        gbl[t + 512] = beta[t];
        float bq4[4];
        #pragma unroll
        for (int nf = 0; nf < 4; ++nf)
            bq4[nf] = (wn < 2) ? bqk[wn * 64 + nf * 16 + mi] : 0.f;
        #pragma unroll
        for (int p2 = 0; p2 < 4; ++p2) {
            if (wm == (p2 >> 1) && wn < 2) {
                #pragma unroll
                for (int mf2 = 0; mf2 < 2; ++mf2) {
                    int mf = ((p2 & 1) << 1) + mf2;
                    #pragma unroll
                    for (int nf = 0; nf < 4; ++nf)
                        #pragma unroll
                        for (int rg = 0; rg < 4; ++rg)
                            epi[(mf2 * 16 + q * 4 + rg) * 132 + wn * 64 + nf * 16 + mi] =
                                silu_f(acc[mf][nf][rg] + bq4[nf]);
                }
            }
            __syncthreads();
            {   // heads 0..2: row-major [32 rows][128 cols]
                int lr = t >> 4, cs = (t & 15) * 8;
                float z[8];
                #pragma unroll
                for (int k = 0; k < 8; ++k) z[k] = epi[lr * 132 + cs + k];
                size_t growr = (size_t)(r0 + p2 * 32 + lr) * QKD + cs;
                #pragma unroll
                for (int hd = 0; hd < 3; ++hd) {
                    bfraw* arr = (hd == 0) ? qq : (hd == 1) ? lq : kk;
                    float tmp[8];
                    #pragma unroll
                    for (int k = 0; k < 8; ++k)
                        tmp[k] = z[k] * gbl[hd * 128 + cs + k] + gbl[512 + hd * 128 + cs + k];
                    store8bf(arr + growr, tmp);
                }
            }
            {   // head 3 -> lkT[bg][c][256] (block-local transpose)
                int c = t >> 2, jh = (t & 3) * 8;
                float g3 = gbl[384 + c], e3 = gbl[896 + c];
                float tmp[8];
                #pragma unroll
                for (int k = 0; k < 8; ++k)
                    tmp[k] = epi[(jh + k) * 132 + c] * g3 + e3;
                store8bf(lkT + ((size_t)bg * QKD + c) * GRP + jb0 + p2 * 32 + jh, tmp);
            }
            __syncthreads();
        }
        return;
    }
    float bias4[4];
    #pragma unroll
    for (int nf = 0; nf < 4; ++nf)
        bias4[nf] = bh[c0 + wn * 64 + nf * 16 + mi];
    if (ct < 4) {
        // v tile -> vT[bg][e][256] (block-local transpose). stride 257.
        #pragma unroll
        for (int p2 = 0; p2 < 4; ++p2) {
            if (wm == (p2 >> 1)) {
                #pragma unroll
                for (int mf2 = 0; mf2 < 2; ++mf2) {
                    int mf = ((p2 & 1) << 1) + mf2;
                    #pragma unroll
                    for (int nf = 0; nf < 4; ++nf)
                        #pragma unroll
                        for (int rg = 0; rg < 4; ++rg)
                            epi[(mf2 * 16 + q * 4 + rg) * 257 + wn * 64 + nf * 16 + mi] =
                                silu_f(acc[mf][nf][rg] + bias4[nf]);
                }
            }
            __syncthreads();
            int e2 = t >> 1, js = (t & 1) * 16;
            float tmp[16];
            #pragma unroll
            for (int k = 0; k < 16; ++k)
                tmp[k] = epi[(js + k) * 257 + e2];
            store16bf(vT + ((size_t)bg * HIDD + c0 + e2) * GRP + jb0 + p2 * 32 + js, tmp);
            __syncthreads();
        }
    } else {
        // gate tile: row-major copy-out. stride 260.
        #pragma unroll
        for (int p2 = 0; p2 < 4; ++p2) {
            if (wm == (p2 >> 1)) {
                #pragma unroll
                for (int mf2 = 0; mf2 < 2; ++mf2) {
                    int mf = ((p2 & 1) << 1) + mf2;
                    #pragma unroll
                    for (int nf = 0; nf < 4; ++nf)
                        #pragma unroll
                        for (int rg = 0; rg < 4; ++rg)
                            epi[(mf2 * 16 + q * 4 + rg) * 260 + wn * 64 + nf * 16 + mi] =
                                silu_f(acc[mf][nf][rg] + bias4[nf]);
                }
            }
            __syncthreads();
            int lr = t >> 4, cs = (t & 15) * 16;
            float tmp[16];
            #pragma unroll
            for (int k = 0; k < 16; ++k)
                tmp[k] = epi[lr * 260 + cs + k];
            store16bf(gate + (size_t)(r0 + p2 * 32 + lr) * HIDD + (c0 - HIDD) + cs, tmp);
            __syncthreads();
        }
    }
}

// ------------- fused sim + kv dispatch.
// blocks 0..511: kv; blocks 512..703: sim.
__global__ __launch_bounds__(256) void simkv_kernel(const bfraw* __restrict__ qq,
                                                    const bfraw* __restrict__ kk,
                                                    bfraw* __restrict__ attn,
                                                    const bfraw* __restrict__ vT,
                                                    const bfraw* __restrict__ lkT,
                                                    bfraw* __restrict__ kvT_raw) {
    SMEMP_DECL
    float* epi = (float*)smem_;
    int t = threadIdx.x;
    int lane = t & 63, wid = t >> 6;
    int wm = wid >> 1, wn = wid & 1;
    int q = lane >> 4, mi = lane & 15;
    int bid = blockIdx.x;
    f32x4 acc[4][4] = {};
    PIPE_DSTS
    if (bid < 512) {
        // ---- kv: kvT_raw[bg][e][d] = sum_j vT[bg][e][j] * lkT[bg][d][j] ----
        int bg = bid >> 3;
        int row0 = (bid & 7) * 128;
        PIPE_LOOP(8, vT + (size_t)bg * HIDD * GRP + (size_t)row0 * GRP, GRP,
                  lkT + (size_t)bg * QKD * GRP, GRP)
        bfraw* outg = kvT_raw + (size_t)bg * HIDD * QKD;
        #pragma unroll
        for (int p = 0; p < 4; ++p) {
            #pragma unroll
            for (int j = 0; j < 4; ++j)
                #pragma unroll
                for (int rg = 0; rg < 4; ++rg)
                    epi[(wm * 16 + q * 4 + rg) * EPIW + wn * 64 + j * 16 + mi] = acc[p][j][rg];
            __syncthreads();
            int lr = t >> 3, c0t = (t & 7) * 16;
            int gr = row0 + epi_row(p, lr);
            store16bf(outg + (size_t)gr * QKD + c0t, &epi[lr * EPIW + c0t]);
            __syncthreads();
        }
        return;
    }
    // ---- sim: attn[bg][i][j] = mask * relu(qq_i . kk_j / G)^2 ----
    int i = bid - 512;
    int bg = i & 63;
    int tid = i >> 6;
    int ry = (tid == 0) ? 0 : 1;
    int rx = (tid == 2) ? 1 : 0;
    int row0 = ry * 128, col0 = rx * 128;
    PIPE_LOOP(4, qq + (size_t)(bg * GRP + row0) * QKD, QKD,
              kk + (size_t)(bg * GRP + col0) * QKD, QKD)
    bfraw* ag = attn + (size_t)bg * GRP * GRP;
    #pragma unroll
    for (int p = 0; p < 4; ++p) {
        #pragma unroll
        for (int j = 0; j < 4; ++j) {
            int colg = col0 + wn * 64 + j * 16 + mi;
            #pragma unroll
            for (int rg = 0; rg < 4; ++rg) {
                int rowg = row0 + wm * 64 + p * 16 + q * 4 + rg;
                float s = acc[p][j][rg] * (1.f / GRP);
                s = fmaxf(s, 0.f);
                s = s * s;
                epi[(wm * 16 + q * 4 + rg) * EPIW + wn * 64 + j * 16 + mi] =
                    (colg > rowg) ? 0.f : s;
            }
        }
        __syncthreads();
        int lr = t >> 3, c0t = (t & 7) * 16;
        int gr = row0 + epi_row(p, lr);
        store16bf(ag + (size_t)gr * GRP + col0 + c0t, &epi[lr * EPIW + c0t]);
        __syncthreads();
    }
}

// ------------- exclusive cumsum over groups (with /G) -------------
__global__ __launch_bounds__(256) void cumsum2_kernel(const bfraw* __restrict__ raw,
                                                      bfraw* __restrict__ ex) {
    int idx = blockIdx.x * 256 + threadIdx.x;
    int b = idx >> 17;
    int r = idx & 131071;
    const bfraw* rp = raw + (size_t)b * NGRP * 131072 + r;
    bfraw* ep = ex + (size_t)b * NGRP * 131072 + r;
    float run = 0.f;
    #pragma unroll
    for (int g = 0; g < NGRP; ++g) {
        ep[(size_t)g * 131072] = f2bf(run);
        run += bf2f(rp[(size_t)g * 131072]) * (1.f / GRP);
    }
}

// ------------- gated = gate .* (attn@vv + lq@kv_ex)  (bf16 out) -------------
__global__ __launch_bounds__(256) void quadlin_mfma(const bfraw* __restrict__ attn,
                                                    const bfraw* __restrict__ vT,
                                                    const bfraw* __restrict__ lq,
                                                    const bfraw* __restrict__ kvT_ex,
                                                    const bfraw* __restrict__ gate,
                                                    bfraw* __restrict__ gated) {
    int bg = blockIdx.z;
    int row0 = blockIdx.y * 128;
    int col0 = blockIdx.x * 128;
    SMEMP_DECL
    float* epi = (float*)smem_;
    int t = threadIdx.x;
    int lane = t & 63, wid = t >> 6;
    int wm = wid >> 1, wn = wid & 1;
    int q = lane >> 4, mi = lane & 15;
    f32x4 acc[4][4] = {};
    PIPE_DSTS
    // Part 1: quadratic. A = attn rows (stride 256), BT = vT rows (stride 256).
    {
        int nit = (row0 + 128) >> 5;     // causal: attn[i][j]=0 for j>i
        PIPE_LOOP(nit, attn + (size_t)bg * GRP * GRP + (size_t)row0 * GRP, GRP,
                  vT + (size_t)bg * HIDD * GRP + (size_t)col0 * GRP, GRP)
    }
    // Part 2: linear. A = lq rows (stride 128), BT = kvT_ex rows (stride 128).
    PIPE_LOOP(4, lq + (size_t)(bg * GRP + row0) * QKD, QKD,
              kvT_ex + (size_t)bg * HIDD * QKD + (size_t)col0 * QKD, QKD)
    #pragma unroll
    for (int p = 0; p < 4; ++p) {
        #pragma unroll
        for (int j = 0; j < 4; ++j)
            #pragma unroll
            for (int rg = 0; rg < 4; ++rg)
                epi[(wm * 16 + q * 4 + rg) * EPIW + wn * 64 + j * 16 + mi] = acc[p][j][rg];
        __syncthreads();
        int lr = t >> 3, c0t = (t & 7) * 16;
        int gr = row0 + epi_row(p, lr);          // group-local row
        size_t grow = (size_t)bg * GRP + gr;
        const float* src = &epi[lr * EPIW + c0t];
        const bfraw* gsrc = gate + grow * HIDD + col0 + c0t;
        u16x8 g0 = *(const u16x8*)gsrc;
        u16x8 g1 = *(const u16x8*)(gsrc + 8);
        float tmp[16];
        #pragma unroll
        for (int k = 0; k < 8; ++k) tmp[k] = src[k] * bf2f(g0[k]);
        #pragma unroll
        for (int k = 0; k < 8; ++k) tmp[8 + k] = src[8 + k] * bf2f(g1[k]);
        store16bf(gated + grow * HIDD + col0 + c0t, tmp);
        __syncthreads();
    }
}

// ======= final: out = gated @ WoT^T + bo + x (16-wave 256x128 engine) =======
__global__ __launch_bounds__(1024, 4) void gemm_final(
    const bfraw* __restrict__ A,      // gated [16384][1024]
    const bfraw* __restrict__ BT,     // WoT [512][1024]
    const float* __restrict__ bo,     // [512]
    const float* __restrict__ x,      // [16384][512]
    float* __restrict__ out) {        // [16384][512]
    __shared__ __align__(16) char smem_[147456];
    const int t = threadIdx.x;
    const int lane = t & 63, wid = t >> 6;
    const int wm = wid >> 2, wn = wid & 3;       // 4M x 4N
    const int q = lane >> 4, mi = lane & 15;
    // XCD swizzle: 256 = 32*8; 4 col-blocks of one row-tile share an XCD.
    int nid = (blockIdx.x & 7) * 32 + (blockIdx.x >> 3);
    const int by = nid >> 2, cx = nid & 3;
    const int r0 = by * 256, c0 = cx * 128;

    const int lslot = (t & 7) ^ ((t >> 3) & 7);
    const int a_row = 2 * (t >> 3) + (lslot >> 2);       // 0..255
    const int a_kel = (lslot & 3) * 8;
    const bfraw* Asrc = A + (size_t)(r0 + a_row) * HIDD + a_kel;
    const int u = t & 511;
    const int lsb = (u & 7) ^ ((u >> 3) & 7);
    const int b_row = 2 * (u >> 3) + (lsb >> 2);         // 0..127
    const int b_kel = (lsb & 3) * 8 + (t >> 9) * 32;
    const bfraw* Bsrc = BT + (size_t)(c0 + b_row) * HIDD + b_kel;

    const int swz = ((((mi & 1) << 2) | q) ^ ((mi >> 1) & 7)) << 4;
    const int a_off = (wm * 32 + (mi >> 1)) * 128 + swz;   // 64 rows/wave
    const int b_off = (wn * 16 + (mi >> 1)) * 128 + swz;   // 32 cols/wave

#define GF_STAGE(SS, SLOT)                                                    \
    do {                                                                      \
        char* sb_ = smem_ + (SLOT) * 49152;                                   \
        gload_lds16(Asrc + (SS) * 64,      sb_ + t * 16);                     \
        gload_lds16(Asrc + (SS) * 64 + 32, sb_ + 16384 + t * 16);             \
        gload_lds16(Bsrc + (SS) * 64,      sb_ + 32768 + t * 16);             \
    } while (0)

    f32x4 acc[4][2] = {};
    GF_STAGE(0, 0);
    GF_STAGE(1, 1);
    asm volatile("s_waitcnt vmcnt(3)" ::: "memory");
    __builtin_amdgcn_s_barrier();

    #pragma unroll
    for (int ss = 0; ss < 16; ++ss) {
        if (ss + 2 < 16) GF_STAGE(ss + 2, (ss + 2) % 3);
        const char* cb = smem_ + (ss % 3) * 49152;
        #pragma unroll
        for (int h = 0; h < 2; ++h) {
            bf16x8 af[4], bfr[2];
            #pragma unroll
            for (int mf = 0; mf < 4; ++mf)
                af[mf] = *(const bf16x8*)(cb + h * 16384 + a_off + mf * 1024);
            #pragma unroll
            for (int nf = 0; nf < 2; ++nf)
                bfr[nf] = *(const bf16x8*)(cb + 32768 + h * 8192 + b_off + nf * 1024);
            __builtin_amdgcn_s_setprio(1);
            #pragma unroll
            for (int mf = 0; mf < 4; ++mf)
                #pragma unroll
                for (int nf = 0; nf < 2; ++nf)
                    acc[mf][nf] = __builtin_amdgcn_mfma_f32_16x16x32_bf16(
                        af[mf], bfr[nf], acc[mf][nf], 0, 0, 0);
            __builtin_amdgcn_s_setprio(0);
        }
        if (ss + 2 < 16)      asm volatile("s_waitcnt vmcnt(3)" ::: "memory");
        else if (ss + 1 < 16) asm volatile("s_waitcnt vmcnt(0)" ::: "memory");
        __builtin_amdgcn_s_barrier();
    }
#undef GF_STAGE

    float* epi = (float*)smem_;
    float bo2[2];
    #pragma unroll
    for (int nf = 0; nf < 2; ++nf)
        bo2[nf] = bo[c0 + wn * 32 + nf * 16 + mi];
    #pragma unroll
    for (int p = 0; p < 4; ++p) {
        if (wm == p) {
            #pragma unroll
            for (int mf = 0; mf < 4; ++mf)
                #pragma unroll
                for (int nf = 0; nf < 2; ++nf)
                    #pragma unroll
                    for (int rg = 0; rg < 4; ++rg)
                        epi[(mf * 16 + q * 4 + rg) * 132 + wn * 32 + nf * 16 + mi] =
                            acc[mf][nf][rg] + bo2[nf];
        }
        __syncthreads();
        int lr = t >> 4, cs = (t & 15) * 8;
        const float* src = epi + lr * 132 + cs;
        const float* xs = x + (size_t)(r0 + p * 64 + lr) * DIMD + c0 + cs;
        float* dst = out + (size_t)(r0 + p * 64 + lr) * DIMD + c0 + cs;
        #pragma unroll
        for (int v = 0; v < 2; ++v) {
            float4 a = ((const float4*)src)[v];
            float4 xv = ((const float4*)xs)[v];
            a.x += xv.x; a.y += xv.y; a.z += xv.z; a.w += xv.w;
            ((float4*)dst)[v] = a;
        }
        __syncthreads();
    }
}

extern "C" void kernel_launch(void* const* d_in, const int* in_sizes, int n_in,
                              void* d_out, int out_size, void* d_ws, size_t ws_size,
                              hipStream_t stream) {
    const float* x     = (const float*)d_in[0];
    const float* ln_w  = (const float*)d_in[1];
    const float* ln_b  = (const float*)d_in[2];
    const float* Wh    = (const float*)d_in[3];
    const float* bh    = (const float*)d_in[4];
    const float* Wqk   = (const float*)d_in[5];
    const float* bqk   = (const float*)d_in[6];
    const float* gamma = (const float*)d_in[7];
    const float* beta  = (const float*)d_in[8];
    const float* Wo    = (const float*)d_in[9];
    const float* bo    = (const float*)d_in[10];
    float* out = (float*)d_out;

    // d_out (32 MiB) hosts short-lived buffers; all dead before gemm_final writes out.
    char* outb_ = (char*)d_out;
    bfraw* attn = (bfraw*)(outb_);                    //  8 MiB [64][256][256]
    bfraw* qq   = (bfraw*)(outb_ + 8388608);          //  4 MiB [16384][128]
    bfraw* kk   = (bfraw*)(outb_ + 12582912);         //  4 MiB
    bfraw* lq   = (bfraw*)(outb_ + 16777216);         //  4 MiB
    bfraw* WhT  = (bfraw*)(outb_ + 20971520);         //  2 MiB [2048][512]
    bfraw* WqkT = (bfraw*)(outb_ + 23068672);         //  128 KiB [128][512]

    // ws layout (byte offsets):
    char* wsb = (char*)d_ws;
    bfraw* vT      = (bfraw*)(wsb);                   // 32 MiB [64][1024][256]
    bfraw* gate    = (bfraw*)(wsb + 33554432);        // 32 MiB [16384][1024]
    bfraw* gated   = (bfraw*)(wsb + 67108864);        // 32 MiB [16384][1024]
    bfraw* normb   = (bfraw*)(wsb + 100663296);       // 16 MiB [16384][512]
    bfraw* kvT_raw = (bfraw*)(wsb + 117440512);       // 16 MiB [64][1024][128]
    bfraw* kvT_ex  = (bfraw*)(wsb + 134217728);       // 16 MiB [64][1024][128]
    bfraw* lkT     = (bfraw*)(wsb + 150994944);       //  4 MiB [64][128][256]
    bfraw* WoT     = (bfraw*)(wsb + 155189248);       //  1 MiB [512][1024]

    // 1. prep: LayerNorm + all weight transposes (one dispatch)
    prep_kernel<<<4096 + 1024 + 512 + 64, 256, 0, stream>>>(
        x, ln_w, ln_b, Wh, Wo, Wqk, normb, WhT, WoT, WqkT);
    // 2. merged h+qk GEMM (128x256, 3-slot 2-resident engine): vT+gate+qq/lq/kk/lkT
    gemm_h256<<<1152, 512, 0, stream>>>(
        normb, WhT, WqkT, bh, bqk, gamma, beta, vT, gate, qq, lq, kk, lkT);
    // 3. fused kv + sim (one dispatch; kv blocks first)
    simkv_kernel<<<512 + 192, 256, 0, stream>>>(qq, kk, attn, vT, lkT, kvT_raw);
    // 4. exclusive cumsum over groups (with /G) -> kvT_ex
    cumsum2_kernel<<<(BATCH * QKD * HIDD) / 256, 256, 0, stream>>>(kvT_raw, kvT_ex);
    // 5. gated = gate .* (attn@vv + lq@kv_ex)
    quadlin_mfma<<<dim3(HIDD / 128, GRP / 128, BGRP), 256, 0, stream>>>(
        attn, vT, lq, kvT_ex, gate, gated);
    // 6. out = gated @ Wo + bo + x  (16-wave 256x128 engine, 256 blocks)
    gemm_final<<<256, 1024, 0, stream>>>(gated, WoT, bo, x, out);
}

// Round 7
// 240.423 us; speedup vs baseline: 1.4174x; 1.0719x over previous
//
#include <hip/hip_runtime.h>
#include <hip/hip_bf16.h>
#include <math.h>

// FLASH (GAU-style) fused block. Round 17: quadlin_mfma ported to the
// twice-verified 8-wave 3-slot-ring engine (R16 gemm_h256 / R14 gemm_final
// pattern): 128x256 tiles, 512 thr, 72KB LDS -> 2 blocks/CU. Two sequential
// pipelined phases (attn@vT causal, then lq@kvT_ex) accumulate into one
// acc[4][4]; gate multiply fused into the copy-out epilogue. Grid 512
// (8x64 XCD swizzle, same-bg blocks share an XCD). All else unchanged from
// R16 (257.7 us).
// b=4, n=4096, dim=512, hid=1024, qk=128, group=256.

#define BATCH 4
#define SEQ   4096
#define TROWS 16384      // BATCH*SEQ
#define DIMD  512
#define HIDD  1024
#define QKD   128
#define GRP   256
#define NGRP  16         // SEQ/GRP
#define BGRP  64         // BATCH*NGRP
#define EPIW  132        // padded LDS epilogue row stride (f32 path, 128-tiles)
#define EPB   130        // bf16 full-tile epilogue row stride (shorts)

typedef unsigned short bfraw;
typedef __attribute__((ext_vector_type(8))) short bf16x8;
typedef __attribute__((ext_vector_type(8))) unsigned short u16x8;
typedef __attribute__((ext_vector_type(4))) unsigned int u32x4;
typedef __attribute__((ext_vector_type(4))) float f32x4;

__device__ __forceinline__ float bf2f(bfraw u) {
    union { float f; unsigned int i; } c;
    c.i = ((unsigned int)u) << 16;
    return c.f;
}
__device__ __forceinline__ bfraw f2bf(float f) {
    unsigned int x = __float_as_uint(f);
    unsigned int r = (x + 0x7fffu + ((x >> 16) & 1u)) >> 16;   // RNE
    return (bfraw)r;
}
__device__ __forceinline__ unsigned int pkbf(float lo, float hi) {
    __hip_bfloat162 h2 = __float22bfloat162_rn(make_float2(lo, hi));
    union { __hip_bfloat162 h; unsigned int u; } c; c.h = h2;
    return c.u;
}
// 16 contiguous f32 -> 16 bf16 at dst (two 16B stores), packed cvt.
__device__ __forceinline__ void store16bf(bfraw* dst, const float* src) {
    u32x4 a, b;
    #pragma unroll
    for (int k = 0; k < 4; ++k) a[k] = pkbf(src[2 * k], src[2 * k + 1]);
    #pragma unroll
    for (int k = 0; k < 4; ++k) b[k] = pkbf(src[8 + 2 * k], src[8 + 2 * k + 1]);
    *(u32x4*)dst = a;
    *(u32x4*)(dst + 8) = b;
}
// 8 contiguous f32 -> 8 bf16 at dst (one 16B store).
__device__ __forceinline__ void store8bf(bfraw* dst, const float* src) {
    u32x4 a;
    #pragma unroll
    for (int k = 0; k < 4; ++k) a[k] = pkbf(src[2 * k], src[2 * k + 1]);
    *(u32x4*)dst = a;
}
__device__ __forceinline__ float silu_f(float z) {
    return z / (1.f + __expf(-z));
}
__device__ __forceinline__ void gload_lds16(const void* g, void* l) {
    __builtin_amdgcn_global_load_lds(
        (const __attribute__((address_space(1))) unsigned int*)g,
        (__attribute__((address_space(3))) unsigned int*)l, 16, 0, 0);
}

// ===================== legacy 128^2 engine (other kernels) =====================
// One BK=32 MFMA step on staged tiles (4 waves, each 64x64 = 4x4 frags).
__device__ __forceinline__ void mfma_step(const bfraw* As, const bfraw* Bs,
                                          f32x4 acc[4][4], int wm, int wn,
                                          int q, int mi) {
    bf16x8 af[4], bfg[4];
    #pragma unroll
    for (int i = 0; i < 4; ++i)
        af[i] = *(const bf16x8*)&As[(size_t)(wm * 64 + i * 16 + mi) * 32 + q * 8];
    #pragma unroll
    for (int j = 0; j < 4; ++j)
        bfg[j] = *(const bf16x8*)&Bs[(size_t)(wn * 64 + j * 16 + mi) * 32 + q * 8];
    #pragma unroll
    for (int i = 0; i < 4; ++i)
        #pragma unroll
        for (int j = 0; j < 4; ++j)
            acc[i][j] = __builtin_amdgcn_mfma_f32_16x16x32_bf16(af[i], bfg[j], acc[i][j], 0, 0, 0);
}

// Double-buffered pipelined K-loop. 33280 bytes: 2x(A 8KB + B 8KB) + epi overlay.
#define SMEMP_DECL                                              \
    __shared__ __align__(16) char smem_[33280];                 \
    bfraw* A0buf = (bfraw*)smem_;                               \
    bfraw* B0buf = (bfraw*)(smem_ + 8192);                      \
    bfraw* A1buf = (bfraw*)(smem_ + 16384);                     \
    bfraw* B1buf = (bfraw*)(smem_ + 24576);

#define PIPE_DSTS                                               \
    bfraw* a0d  = A0buf + wid * 512;                            \
    bfraw* a0d2 = A0buf + 2048 + wid * 512;                     \
    bfraw* b0d  = B0buf + wid * 512;                            \
    bfraw* b0d2 = B0buf + 2048 + wid * 512;                     \
    bfraw* a1d  = A1buf + wid * 512;                            \
    bfraw* a1d2 = A1buf + 2048 + wid * 512;                     \
    bfraw* b1d  = B1buf + wid * 512;                            \
    bfraw* b1d2 = B1buf + 2048 + wid * 512;

#define KLOOP_PRE(Abase, Astr, Bbase, Bstr)                                    \
    const bfraw* pa0 = (Abase) + (size_t)(t >> 2) * (Astr) + (t & 3) * 8;      \
    const bfraw* pa1 = pa0 + (size_t)64 * (Astr);                              \
    const bfraw* pb0 = (Bbase) + (size_t)(t >> 2) * (Bstr) + (t & 3) * 8;      \
    const bfraw* pb1 = pb0 + (size_t)64 * (Bstr);

#define STAGE0                                                                 \
    do { gload_lds16(pa0, a0d); gload_lds16(pa1, a0d2);                        \
         gload_lds16(pb0, b0d); gload_lds16(pb1, b0d2);                        \
         pa0 += 32; pa1 += 32; pb0 += 32; pb1 += 32; } while (0)
#define STAGE1                                                                 \
    do { gload_lds16(pa0, a1d); gload_lds16(pa1, a1d2);                        \
         gload_lds16(pb0, b1d); gload_lds16(pb1, b1d2);                        \
         pa0 += 32; pa1 += 32; pb0 += 32; pb1 += 32; } while (0)

// NIT must be even (all call sites: K/32 ∈ {4,8,16,32}).
#define PIPE_LOOP(NIT, Abase, Astr, Bbase, Bstr)                               \
    {                                                                          \
        KLOOP_PRE(Abase, Astr, Bbase, Bstr)                                    \
        STAGE0;                                                                \
        for (int it = 0; it < (NIT); it += 2) {                                \
            __syncthreads();                                                   \
            if (it + 1 < (NIT)) STAGE1;                                        \
            mfma_step(A0buf, B0buf, acc, wm, wn, q, mi);                       \
            __syncthreads();                                                   \
            if (it + 2 < (NIT)) STAGE0;                                        \
            if (it + 1 < (NIT))                                                \
                mfma_step(A1buf, B1buf, acc, wm, wn, q, mi);                   \
        }                                                                      \
        __syncthreads();                                                       \
    }

__device__ __forceinline__ int epi_row(int p, int lr) {
    return (lr < 16) ? (p * 16 + lr) : (64 + p * 16 + (lr - 16));
}

// ------------- prep: ln (blocks 0..4095) + 3 weight transposes -------------
__global__ __launch_bounds__(256) void prep_kernel(const float* __restrict__ x,
                                                   const float* __restrict__ lnw,
                                                   const float* __restrict__ lnb,
                                                   const float* __restrict__ Wh,
                                                   const float* __restrict__ Wo,
                                                   const float* __restrict__ Wqk,
                                                   bfraw* __restrict__ normb,
                                                   bfraw* __restrict__ WhT,
                                                   bfraw* __restrict__ WoT,
                                                   bfraw* __restrict__ WqkT) {
    __shared__ float tile[32][33];
    int bid = blockIdx.x;
    int t = threadIdx.x;
    if (bid < 4096) {
        int row  = bid * 4 + (t >> 6);
        int lane = t & 63;
        const float* xr = x + (size_t)row * DIMD;
        float4 v0 = ((const float4*)xr)[lane];
        float4 v1 = ((const float4*)xr)[lane + 64];
        float s  = v0.x + v0.y + v0.z + v0.w + v1.x + v1.y + v1.z + v1.w;
        float ss = v0.x*v0.x + v0.y*v0.y + v0.z*v0.z + v0.w*v0.w
                 + v1.x*v1.x + v1.y*v1.y + v1.z*v1.z + v1.w*v1.w;
        #pragma unroll
        for (int off = 32; off; off >>= 1) {
            s  += __shfl_xor(s, off);
            ss += __shfl_xor(ss, off);
        }
        float mu  = s * (1.f / DIMD);
        float var = ss * (1.f / DIMD) - mu * mu;
        float inv = rsqrtf(var + 1e-5f);
        float4 w0 = ((const float4*)lnw)[lane],  w1 = ((const float4*)lnw)[lane + 64];
        float4 b0 = ((const float4*)lnb)[lane],  b1 = ((const float4*)lnb)[lane + 64];
        unsigned int o0 = pkbf((v0.x - mu) * inv * w0.x + b0.x,
                               (v0.y - mu) * inv * w0.y + b0.y);
        unsigned int o1 = pkbf((v0.z - mu) * inv * w0.z + b0.z,
                               (v0.w - mu) * inv * w0.w + b0.w);
        unsigned int o2 = pkbf((v1.x - mu) * inv * w1.x + b1.x,
                               (v1.y - mu) * inv * w1.y + b1.y);
        unsigned int o3 = pkbf((v1.z - mu) * inv * w1.z + b1.z,
                               (v1.w - mu) * inv * w1.w + b1.w);
        unsigned int* brow = (unsigned int*)(normb + (size_t)row * DIMD);
        ((uint2*)brow)[lane]      = make_uint2(o0, o1);
        ((uint2*)brow)[lane + 64] = make_uint2(o2, o3);
        return;
    }
    bid -= 4096;
    const float* in; bfraw* outp; int R, C, nx;
    if (bid < 1024)      { in = Wh;  outp = WhT;  R = DIMD; C = 2 * HIDD; nx = 64; }
    else if (bid < 1536) { bid -= 1024; in = Wo;  outp = WoT;  R = HIDD; C = DIMD; nx = 16; }
    else                 { bid -= 1536; in = Wqk; outp = WqkT; R = DIMD; C = QKD;  nx = 4; }
    int c0 = (bid % nx) * 32, r0 = (bid / nx) * 32;
    int tr = t >> 3, tc4 = (t & 7) * 4;
    float4 v = *(const float4*)&in[(size_t)(r0 + tr) * C + c0 + tc4];
    tile[tr][tc4 + 0] = v.x; tile[tr][tc4 + 1] = v.y;
    tile[tr][tc4 + 2] = v.z; tile[tr][tc4 + 3] = v.w;
    __syncthreads();
    ushort4 s;
    s.x = f2bf(tile[tc4 + 0][tr]);
    s.y = f2bf(tile[tc4 + 1][tr]);
    s.z = f2bf(tile[tc4 + 2][tr]);
    s.w = f2bf(tile[tc4 + 3][tr]);
    *(ushort4*)&outp[(size_t)(c0 + tr) * R + r0 + tc4] = s;
}

// ========== 128x256-tile, 8-wave (512-thr), 3-slot-ring h+qk GEMM ==========
__global__ __launch_bounds__(512, 4) void gemm_h256(
    const bfraw* __restrict__ A,      // normb [16384][512]
    const bfraw* __restrict__ WhT,    // [2048][512]
    const bfraw* __restrict__ WqkT,   // [128][512]
    const float* __restrict__ bh,     // [2048]
    const float* __restrict__ bqk,    // [128]
    const float* __restrict__ gamma,  // [4][128]
    const float* __restrict__ beta,   // [4][128]
    bfraw* __restrict__ vT,
    bfraw* __restrict__ gate,
    bfraw* __restrict__ qq,
    bfraw* __restrict__ lq,
    bfraw* __restrict__ kk,
    bfraw* __restrict__ lkT) {
    __shared__ __align__(16) char smem_[73728];
    const int t = threadIdx.x;
    const int lane = t & 63, wid = t >> 6;
    const int wm = wid >> 2, wn = wid & 3;       // 2M x 4N wave grid
    const int q = lane >> 4, mi = lane & 15;
    // XCD swizzle: 1152 = 8*144; per XCD: 16 by-strips x their 9 ct tiles.
    int nid = (blockIdx.x & 7) * 144 + (blockIdx.x >> 3);
    const int ct = nid % 9, by = nid / 9;        // by 0..127
    const int r0 = by * 128, c0 = ct * 256;
    const int bg = r0 >> 8;                      // group index
    const int jb0 = r0 & 255;                    // row offset within group

    const int lslot = (t & 7) ^ ((t >> 3) & 7);
    const int srow  = 2 * (t >> 3) + (lslot >> 2);      // 0..127
    const int skel  = (lslot & 3) * 8;
    const bfraw* Asrc = A + (size_t)(r0 + srow) * DIMD + skel;
    const bfraw* Bsrc0;
    const bfraw* Bsrc1;
    if (ct < 8) {
        Bsrc0 = WhT + (size_t)(c0 + srow) * DIMD + skel;
        Bsrc1 = Bsrc0 + (size_t)128 * DIMD;
    } else {
        Bsrc0 = WqkT + (size_t)srow * DIMD + skel;   // rows 0..127 real
        Bsrc1 = Bsrc0;                               // cols 128..255 garbage dup
    }
    const int swz = ((((mi & 1) << 2) | q) ^ ((mi >> 1) & 7)) << 4;
    const int a_off = (wm * 32 + (mi >> 1)) * 128 + swz;   // 64 rows/wave
    const int b_off = (wn * 32 + (mi >> 1)) * 128 + swz;   // 64 cols/wave

#define GH_STAGE(KT, SLOT)                                                    \
    do {                                                                      \
        char* sb_ = smem_ + (SLOT) * 24576;                                   \
        gload_lds16(Asrc  + (KT) * 32, sb_ + t * 16);                         \
        gload_lds16(Bsrc0 + (KT) * 32, sb_ + 8192 + t * 16);                  \
        gload_lds16(Bsrc1 + (KT) * 32, sb_ + 16384 + t * 16);                 \
    } while (0)

    f32x4 acc[4][4] = {};
    GH_STAGE(0, 0);
    GH_STAGE(1, 1);
    asm volatile("s_waitcnt vmcnt(3)" ::: "memory");   // stage(0) landed
    __builtin_amdgcn_s_barrier();

    #pragma unroll
    for (int j = 0; j < 16; ++j) {
        if (j + 2 < 16) GH_STAGE(j + 2, (j + 2) % 3);
        const char* cb = smem_ + (j % 3) * 24576;
        bf16x8 af[4], bfr[4];
        #pragma unroll
        for (int mf = 0; mf < 4; ++mf)
            af[mf] = *(const bf16x8*)(cb + a_off + mf * 1024);
        #pragma unroll
        for (int nf = 0; nf < 4; ++nf)
            bfr[nf] = *(const bf16x8*)(cb + 8192 + b_off + nf * 1024);
        __builtin_amdgcn_s_setprio(1);
        #pragma unroll
        for (int mf = 0; mf < 4; ++mf)
            #pragma unroll
            for (int nf = 0; nf < 4; ++nf)
                acc[mf][nf] = __builtin_amdgcn_mfma_f32_16x16x32_bf16(
                    af[mf], bfr[nf], acc[mf][nf], 0, 0, 0);
        __builtin_amdgcn_s_setprio(0);
        if (j + 2 < 16)      asm volatile("s_waitcnt vmcnt(3)" ::: "memory");
        else if (j + 1 < 16) asm volatile("s_waitcnt vmcnt(0)" ::: "memory");
        __builtin_amdgcn_s_barrier();
    }
#undef GH_STAGE

    float* epi = (float*)smem_;
    if (ct == 8) {
        float* gbl = (float*)(smem_ + 36864);    // gamma[512] | beta[512]
        gbl[t] = gamma[t];
        gbl[t + 512] = beta[t];
        float bq4[4];
        #pragma unroll
        for (int nf = 0; nf < 4; ++nf)
            bq4[nf] = (wn < 2) ? bqk[wn * 64 + nf * 16 + mi] : 0.f;
        #pragma unroll
        for (int p2 = 0; p2 < 4; ++p2) {
            if (wm == (p2 >> 1) && wn < 2) {
                #pragma unroll
                for (int mf2 = 0; mf2 < 2; ++mf2) {
                    int mf = ((p2 & 1) << 1) + mf2;
                    #pragma unroll
                    for (int nf = 0; nf < 4; ++nf)
                        #pragma unroll
                        for (int rg = 0; rg < 4; ++rg)
                            epi[(mf2 * 16 + q * 4 + rg) * 132 + wn * 64 + nf * 16 + mi] =
                                silu_f(acc[mf][nf][rg] + bq4[nf]);
                }
            }
            __syncthreads();
            {   // heads 0..2: row-major [32 rows][128 cols]
                int lr = t >> 4, cs = (t & 15) * 8;
                float z[8];
                #pragma unroll
                for (int k = 0; k < 8; ++k) z[k] = epi[lr * 132 + cs + k];
                size_t growr = (size_t)(r0 + p2 * 32 + lr) * QKD + cs;
                #pragma unroll
                for (int hd = 0; hd < 3; ++hd) {
                    bfraw* arr = (hd == 0) ? qq : (hd == 1) ? lq : kk;
                    float tmp[8];
                    #pragma unroll
                    for (int k = 0; k < 8; ++k)
                        tmp[k] = z[k] * gbl[hd * 128 + cs + k] + gbl[512 + hd * 128 + cs + k];
                    store8bf(arr + growr, tmp);
                }
            }
            {   // head 3 -> lkT[bg][c][256] (block-local transpose)
                int c = t >> 2, jh = (t & 3) * 8;
                float g3 = gbl[384 + c], e3 = gbl[896 + c];
                float tmp[8];
                #pragma unroll
                for (int k = 0; k < 8; ++k)
                    tmp[k] = epi[(jh + k) * 132 + c] * g3 + e3;
                store8bf(lkT + ((size_t)bg * QKD + c) * GRP + jb0 + p2 * 32 + jh, tmp);
            }
            __syncthreads();
        }
        return;
    }
    float bias4[4];
    #pragma unroll
    for (int nf = 0; nf < 4; ++nf)
        bias4[nf] = bh[c0 + wn * 64 + nf * 16 + mi];
    if (ct < 4) {
        // v tile -> vT[bg][e][256] (block-local transpose). stride 257.
        #pragma unroll
        for (int p2 = 0; p2 < 4; ++p2) {
            if (wm == (p2 >> 1)) {
                #pragma unroll
                for (int mf2 = 0; mf2 < 2; ++mf2) {
                    int mf = ((p2 & 1) << 1) + mf2;
                    #pragma unroll
                    for (int nf = 0; nf < 4; ++nf)
                        #pragma unroll
                        for (int rg = 0; rg < 4; ++rg)
                            epi[(mf2 * 16 + q * 4 + rg) * 257 + wn * 64 + nf * 16 + mi] =
                                silu_f(acc[mf][nf][rg] + bias4[nf]);
                }
            }
            __syncthreads();
            int e2 = t >> 1, js = (t & 1) * 16;
            float tmp[16];
            #pragma unroll
            for (int k = 0; k < 16; ++k)
                tmp[k] = epi[(js + k) * 257 + e2];
            store16bf(vT + ((size_t)bg * HIDD + c0 + e2) * GRP + jb0 + p2 * 32 + js, tmp);
            __syncthreads();
        }
    } else {
        // gate tile: row-major copy-out. stride 260.
        #pragma unroll
        for (int p2 = 0; p2 < 4; ++p2) {
            if (wm == (p2 >> 1)) {
                #pragma unroll
                for (int mf2 = 0; mf2 < 2; ++mf2) {
                    int mf = ((p2 & 1) << 1) + mf2;
                    #pragma unroll
                    for (int nf = 0; nf < 4; ++nf)
                        #pragma unroll
                        for (int rg = 0; rg < 4; ++rg)
                            epi[(mf2 * 16 + q * 4 + rg) * 260 + wn * 64 + nf * 16 + mi] =
                                silu_f(acc[mf][nf][rg] + bias4[nf]);
                }
            }
            __syncthreads();
            int lr = t >> 4, cs = (t & 15) * 16;
            float tmp[16];
            #pragma unroll
            for (int k = 0; k < 16; ++k)
                tmp[k] = epi[lr * 260 + cs + k];
            store16bf(gate + (size_t)(r0 + p2 * 32 + lr) * HIDD + (c0 - HIDD) + cs, tmp);
            __syncthreads();
        }
    }
}

// ------------- fused sim + kv dispatch.
// blocks 0..511: kv; blocks 512..703: sim.
__global__ __launch_bounds__(256) void simkv_kernel(const bfraw* __restrict__ qq,
                                                    const bfraw* __restrict__ kk,
                                                    bfraw* __restrict__ attn,
                                                    const bfraw* __restrict__ vT,
                                                    const bfraw* __restrict__ lkT,
                                                    bfraw* __restrict__ kvT_raw) {
    SMEMP_DECL
    float* epi = (float*)smem_;
    int t = threadIdx.x;
    int lane = t & 63, wid = t >> 6;
    int wm = wid >> 1, wn = wid & 1;
    int q = lane >> 4, mi = lane & 15;
    int bid = blockIdx.x;
    f32x4 acc[4][4] = {};
    PIPE_DSTS
    if (bid < 512) {
        // ---- kv: kvT_raw[bg][e][d] = sum_j vT[bg][e][j] * lkT[bg][d][j] ----
        int bg = bid >> 3;
        int row0 = (bid & 7) * 128;
        PIPE_LOOP(8, vT + (size_t)bg * HIDD * GRP + (size_t)row0 * GRP, GRP,
                  lkT + (size_t)bg * QKD * GRP, GRP)
        bfraw* outg = kvT_raw + (size_t)bg * HIDD * QKD;
        #pragma unroll
        for (int p = 0; p < 4; ++p) {
            #pragma unroll
            for (int j = 0; j < 4; ++j)
                #pragma unroll
                for (int rg = 0; rg < 4; ++rg)
                    epi[(wm * 16 + q * 4 + rg) * EPIW + wn * 64 + j * 16 + mi] = acc[p][j][rg];
            __syncthreads();
            int lr = t >> 3, c0t = (t & 7) * 16;
            int gr = row0 + epi_row(p, lr);
            store16bf(outg + (size_t)gr * QKD + c0t, &epi[lr * EPIW + c0t]);
            __syncthreads();
        }
        return;
    }
    // ---- sim: attn[bg][i][j] = mask * relu(qq_i . kk_j / G)^2 ----
    int i = bid - 512;
    int bg = i & 63;
    int tid = i >> 6;
    int ry = (tid == 0) ? 0 : 1;
    int rx = (tid == 2) ? 1 : 0;
    int row0 = ry * 128, col0 = rx * 128;
    PIPE_LOOP(4, qq + (size_t)(bg * GRP + row0) * QKD, QKD,
              kk + (size_t)(bg * GRP + col0) * QKD, QKD)
    bfraw* ag = attn + (size_t)bg * GRP * GRP;
    #pragma unroll
    for (int p = 0; p < 4; ++p) {
        #pragma unroll
        for (int j = 0; j < 4; ++j) {
            int colg = col0 + wn * 64 + j * 16 + mi;
            #pragma unroll
            for (int rg = 0; rg < 4; ++rg) {
                int rowg = row0 + wm * 64 + p * 16 + q * 4 + rg;
                float s = acc[p][j][rg] * (1.f / GRP);
                s = fmaxf(s, 0.f);
                s = s * s;
                epi[(wm * 16 + q * 4 + rg) * EPIW + wn * 64 + j * 16 + mi] =
                    (colg > rowg) ? 0.f : s;
            }
        }
        __syncthreads();
        int lr = t >> 3, c0t = (t & 7) * 16;
        int gr = row0 + epi_row(p, lr);
        store16bf(ag + (size_t)gr * GRP + col0 + c0t, &epi[lr * EPIW + c0t]);
        __syncthreads();
    }
}

// ------------- exclusive cumsum over groups (with /G) -------------
__global__ __launch_bounds__(256) void cumsum2_kernel(const bfraw* __restrict__ raw,
                                                      bfraw* __restrict__ ex) {
    int idx = blockIdx.x * 256 + threadIdx.x;
    int b = idx >> 17;
    int r = idx & 131071;
    const bfraw* rp = raw + (size_t)b * NGRP * 131072 + r;
    bfraw* ep = ex + (size_t)b * NGRP * 131072 + r;
    float run = 0.f;
    #pragma unroll
    for (int g = 0; g < NGRP; ++g) {
        ep[(size_t)g * 131072] = f2bf(run);
        run += bf2f(rp[(size_t)g * 131072]) * (1.f / GRP);
    }
}

// ==== gated = gate .* (attn@vv + lq@kv_ex) — 8-wave 3-slot-ring engine ====
// Grid: 512 blocks (8x64 XCD swizzle: same-bg blocks share an XCD), 512 thr.
// Tile: 128 group-rows x 256 HIDD-cols. Two sequential pipelined phases
// accumulate into one acc[4][4]: P1 attn@vT (K = row0+128 causal, stride 256),
// P2 lq@kvT_ex (K = 128, stride 128). Gate fused into copy-out.
__global__ __launch_bounds__(512, 4) void quadlin256(
    const bfraw* __restrict__ attn,    // [64][256][256]
    const bfraw* __restrict__ vT,      // [64][1024][256]
    const bfraw* __restrict__ lq,      // [16384][128]
    const bfraw* __restrict__ kvT_ex,  // [64][1024][128]
    const bfraw* __restrict__ gate,    // [16384][1024]
    bfraw* __restrict__ gated) {       // [16384][1024]
    __shared__ __align__(16) char smem_[73728];
    const int t = threadIdx.x;
    const int lane = t & 63, wid = t >> 6;
    const int wm = wid >> 2, wn = wid & 3;       // 2M x 4N wave grid
    const int q = lane >> 4, mi = lane & 15;
    // XCD swizzle: 512 = 8*64; bg = nid>>3 -> each XCD owns 8 groups.
    int nid = (blockIdx.x & 7) * 64 + (blockIdx.x >> 3);
    const int bg = nid >> 3;
    const int row0 = ((nid >> 2) & 1) * 128;
    const int c0 = (nid & 3) * 256;

    const int lslot = (t & 7) ^ ((t >> 3) & 7);
    const int srow  = 2 * (t >> 3) + (lslot >> 2);      // 0..127
    const int skel  = (lslot & 3) * 8;
    // P1 sources (stride GRP=256)
    const bfraw* A1 = attn + ((size_t)bg * GRP + row0 + srow) * GRP + skel;
    const bfraw* B1a = vT + ((size_t)bg * HIDD + c0 + srow) * GRP + skel;
    const bfraw* B1b = B1a + (size_t)128 * GRP;
    // P2 sources (stride QKD=128)
    const bfraw* A2 = lq + ((size_t)bg * GRP + row0 + srow) * QKD + skel;
    const bfraw* B2a = kvT_ex + ((size_t)bg * HIDD + c0 + srow) * QKD + skel;
    const bfraw* B2b = B2a + (size_t)128 * QKD;

    const int swz = ((((mi & 1) << 2) | q) ^ ((mi >> 1) & 7)) << 4;
    const int a_off = (wm * 32 + (mi >> 1)) * 128 + swz;   // 64 rows/wave
    const int b_off = (wn * 32 + (mi >> 1)) * 128 + swz;   // 64 cols/wave

#define QL_STAGE(PA, PB0, PB1, KT, SLOT)                                      \
    do {                                                                      \
        char* sb_ = smem_ + (SLOT) * 24576;                                   \
        gload_lds16((PA)  + (KT) * 32, sb_ + t * 16);                         \
        gload_lds16((PB0) + (KT) * 32, sb_ + 8192 + t * 16);                  \
        gload_lds16((PB1) + (KT) * 32, sb_ + 16384 + t * 16);                 \
    } while (0)
#define QL_MFMA(SLOT)                                                         \
    do {                                                                      \
        const char* cb = smem_ + (SLOT) * 24576;                              \
        bf16x8 af[4], bfr[4];                                                 \
        _Pragma("unroll")                                                     \
        for (int mf = 0; mf < 4; ++mf)                                        \
            af[mf] = *(const bf16x8*)(cb + a_off + mf * 1024);                \
        _Pragma("unroll")                                                     \
        for (int nf = 0; nf < 4; ++nf)                                        \
            bfr[nf] = *(const bf16x8*)(cb + 8192 + b_off + nf * 1024);        \
        __builtin_amdgcn_s_setprio(1);                                        \
        _Pragma("unroll")                                                     \
        for (int mf = 0; mf < 4; ++mf)                                        \
            _Pragma("unroll")                                                 \
            for (int nf = 0; nf < 4; ++nf)                                    \
                acc[mf][nf] = __builtin_amdgcn_mfma_f32_16x16x32_bf16(        \
                    af[mf], bfr[nf], acc[mf][nf], 0, 0, 0);                   \
        __builtin_amdgcn_s_setprio(0);                                        \
    } while (0)

    f32x4 acc[4][4] = {};
    const int nit1 = (row0 + 128) >> 5;     // 4 or 8 (causal)
    // ---- phase 1: attn @ vT ----
    QL_STAGE(A1, B1a, B1b, 0, 0);
    QL_STAGE(A1, B1a, B1b, 1, 1);
    asm volatile("s_waitcnt vmcnt(3)" ::: "memory");
    __builtin_amdgcn_s_barrier();
    for (int j = 0; j < nit1; ++j) {
        if (j + 2 < nit1) QL_STAGE(A1, B1a, B1b, j + 2, (j + 2) % 3);
        QL_MFMA(j % 3);
        if (j + 2 < nit1)      asm volatile("s_waitcnt vmcnt(3)" ::: "memory");
        else if (j + 1 < nit1) asm volatile("s_waitcnt vmcnt(0)" ::: "memory");
        __builtin_amdgcn_s_barrier();
    }
    // ---- phase 2: lq @ kvT_ex (4 steps) ----
    QL_STAGE(A2, B2a, B2b, 0, 0);
    QL_STAGE(A2, B2a, B2b, 1, 1);
    asm volatile("s_waitcnt vmcnt(3)" ::: "memory");
    __builtin_amdgcn_s_barrier();
    #pragma unroll
    for (int j = 0; j < 4; ++j) {
        if (j + 2 < 4) QL_STAGE(A2, B2a, B2b, j + 2, (j + 2) % 3);
        QL_MFMA(j % 3);
        if (j + 2 < 4)      asm volatile("s_waitcnt vmcnt(3)" ::: "memory");
        else if (j + 1 < 4) asm volatile("s_waitcnt vmcnt(0)" ::: "memory");
        __builtin_amdgcn_s_barrier();
    }
#undef QL_STAGE
#undef QL_MFMA

    // ---- epilogue: 4 phases of 32 rows; gate multiply fused. stride 260.
    float* epi = (float*)smem_;
    #pragma unroll
    for (int p2 = 0; p2 < 4; ++p2) {
        if (wm == (p2 >> 1)) {
            #pragma unroll
            for (int mf2 = 0; mf2 < 2; ++mf2) {
                int mf = ((p2 & 1) << 1) + mf2;
                #pragma unroll
                for (int nf = 0; nf < 4; ++nf)
                    #pragma unroll
                    for (int rg = 0; rg < 4; ++rg)
                        epi[(mf2 * 16 + q * 4 + rg) * 260 + wn * 64 + nf * 16 + mi] =
                            acc[mf][nf][rg];
            }
        }
        __syncthreads();
        int lr = t >> 4, cs = (t & 15) * 16;
        size_t grow = (size_t)bg * GRP + row0 + p2 * 32 + lr;
        const float* src = epi + lr * 260 + cs;
        const bfraw* gsrc = gate + grow * HIDD + c0 + cs;
        u16x8 g0 = *(const u16x8*)gsrc;
        u16x8 g1 = *(const u16x8*)(gsrc + 8);
        float tmp[16];
        #pragma unroll
        for (int k = 0; k < 8; ++k) tmp[k] = src[k] * bf2f(g0[k]);
        #pragma unroll
        for (int k = 0; k < 8; ++k) tmp[8 + k] = src[8 + k] * bf2f(g1[k]);
        store16bf(gated + grow * HIDD + c0 + cs, tmp);
        __syncthreads();
    }
}

// ======= final: out = gated @ WoT^T + bo + x (16-wave 256x128 engine) =======
__global__ __launch_bounds__(1024, 4) void gemm_final(
    const bfraw* __restrict__ A,      // gated [16384][1024]
    const bfraw* __restrict__ BT,     // WoT [512][1024]
    const float* __restrict__ bo,     // [512]
    const float* __restrict__ x,      // [16384][512]
    float* __restrict__ out) {        // [16384][512]
    __shared__ __align__(16) char smem_[147456];
    const int t = threadIdx.x;
    const int lane = t & 63, wid = t >> 6;
    const int wm = wid >> 2, wn = wid & 3;       // 4M x 4N
    const int q = lane >> 4, mi = lane & 15;
    // XCD swizzle: 256 = 32*8; 4 col-blocks of one row-tile share an XCD.
    int nid = (blockIdx.x & 7) * 32 + (blockIdx.x >> 3);
    const int by = nid >> 2, cx = nid & 3;
    const int r0 = by * 256, c0 = cx * 128;

    const int lslot = (t & 7) ^ ((t >> 3) & 7);
    const int a_row = 2 * (t >> 3) + (lslot >> 2);       // 0..255
    const int a_kel = (lslot & 3) * 8;
    const bfraw* Asrc = A + (size_t)(r0 + a_row) * HIDD + a_kel;
    const int u = t & 511;
    const int lsb = (u & 7) ^ ((u >> 3) & 7);
    const int b_row = 2 * (u >> 3) + (lsb >> 2);         // 0..127
    const int b_kel = (lsb & 3) * 8 + (t >> 9) * 32;
    const bfraw* Bsrc = BT + (size_t)(c0 + b_row) * HIDD + b_kel;

    const int swz = ((((mi & 1) << 2) | q) ^ ((mi >> 1) & 7)) << 4;
    const int a_off = (wm * 32 + (mi >> 1)) * 128 + swz;   // 64 rows/wave
    const int b_off = (wn * 16 + (mi >> 1)) * 128 + swz;   // 32 cols/wave

#define GF_STAGE(SS, SLOT)                                                    \
    do {                                                                      \
        char* sb_ = smem_ + (SLOT) * 49152;                                   \
        gload_lds16(Asrc + (SS) * 64,      sb_ + t * 16);                     \
        gload_lds16(Asrc + (SS) * 64 + 32, sb_ + 16384 + t * 16);             \
        gload_lds16(Bsrc + (SS) * 64,      sb_ + 32768 + t * 16);             \
    } while (0)

    f32x4 acc[4][2] = {};
    GF_STAGE(0, 0);
    GF_STAGE(1, 1);
    asm volatile("s_waitcnt vmcnt(3)" ::: "memory");
    __builtin_amdgcn_s_barrier();

    #pragma unroll
    for (int ss = 0; ss < 16; ++ss) {
        if (ss + 2 < 16) GF_STAGE(ss + 2, (ss + 2) % 3);
        const char* cb = smem_ + (ss % 3) * 49152;
        #pragma unroll
        for (int h = 0; h < 2; ++h) {
            bf16x8 af[4], bfr[2];
            #pragma unroll
            for (int mf = 0; mf < 4; ++mf)
                af[mf] = *(const bf16x8*)(cb + h * 16384 + a_off + mf * 1024);
            #pragma unroll
            for (int nf = 0; nf < 2; ++nf)
                bfr[nf] = *(const bf16x8*)(cb + 32768 + h * 8192 + b_off + nf * 1024);
            __builtin_amdgcn_s_setprio(1);
            #pragma unroll
            for (int mf = 0; mf < 4; ++mf)
                #pragma unroll
                for (int nf = 0; nf < 2; ++nf)
                    acc[mf][nf] = __builtin_amdgcn_mfma_f32_16x16x32_bf16(
                        af[mf], bfr[nf], acc[mf][nf], 0, 0, 0);
            __builtin_amdgcn_s_setprio(0);
        }
        if (ss + 2 < 16)      asm volatile("s_waitcnt vmcnt(3)" ::: "memory");
        else if (ss + 1 < 16) asm volatile("s_waitcnt vmcnt(0)" ::: "memory");
        __builtin_amdgcn_s_barrier();
    }
#undef GF_STAGE

    float* epi = (float*)smem_;
    float bo2[2];
    #pragma unroll
    for (int nf = 0; nf < 2; ++nf)
        bo2[nf] = bo[c0 + wn * 32 + nf * 16 + mi];
    #pragma unroll
    for (int p = 0; p < 4; ++p) {
        if (wm == p) {
            #pragma unroll
            for (int mf = 0; mf < 4; ++mf)
                #pragma unroll
                for (int nf = 0; nf < 2; ++nf)
                    #pragma unroll
                    for (int rg = 0; rg < 4; ++rg)
                        epi[(mf * 16 + q * 4 + rg) * 132 + wn * 32 + nf * 16 + mi] =
                            acc[mf][nf][rg] + bo2[nf];
        }
        __syncthreads();
        int lr = t >> 4, cs = (t & 15) * 8;
        const float* src = epi + lr * 132 + cs;
        const float* xs = x + (size_t)(r0 + p * 64 + lr) * DIMD + c0 + cs;
        float* dst = out + (size_t)(r0 + p * 64 + lr) * DIMD + c0 + cs;
        #pragma unroll
        for (int v = 0; v < 2; ++v) {
            float4 a = ((const float4*)src)[v];
            float4 xv = ((const float4*)xs)[v];
            a.x += xv.x; a.y += xv.y; a.z += xv.z; a.w += xv.w;
            ((float4*)dst)[v] = a;
        }
        __syncthreads();
    }
}

extern "C" void kernel_launch(void* const* d_in, const int* in_sizes, int n_in,
                              void* d_out, int out_size, void* d_ws, size_t ws_size,
                              hipStream_t stream) {
    const float* x     = (const float*)d_in[0];
    const float* ln_w  = (const float*)d_in[1];
    const float* ln_b  = (const float*)d_in[2];
    const float* Wh    = (const float*)d_in[3];
    const float* bh    = (const float*)d_in[4];
    const float* Wqk   = (const float*)d_in[5];
    const float* bqk   = (const float*)d_in[6];
    const float* gamma = (const float*)d_in[7];
    const float* beta  = (const float*)d_in[8];
    const float* Wo    = (const float*)d_in[9];
    const float* bo    = (const float*)d_in[10];
    float* out = (float*)d_out;

    // d_out (32 MiB) hosts short-lived buffers; all dead before gemm_final writes out.
    char* outb_ = (char*)d_out;
    bfraw* attn = (bfraw*)(outb_);                    //  8 MiB [64][256][256]
    bfraw* qq   = (bfraw*)(outb_ + 8388608);          //  4 MiB [16384][128]
    bfraw* kk   = (bfraw*)(outb_ + 12582912);         //  4 MiB
    bfraw* lq   = (bfraw*)(outb_ + 16777216);         //  4 MiB
    bfraw* WhT  = (bfraw*)(outb_ + 20971520);         //  2 MiB [2048][512]
    bfraw* WqkT = (bfraw*)(outb_ + 23068672);         //  128 KiB [128][512]

    // ws layout (byte offsets):
    char* wsb = (char*)d_ws;
    bfraw* vT      = (bfraw*)(wsb);                   // 32 MiB [64][1024][256]
    bfraw* gate    = (bfraw*)(wsb + 33554432);        // 32 MiB [16384][1024]
    bfraw* gated   = (bfraw*)(wsb + 67108864);        // 32 MiB [16384][1024]
    bfraw* normb   = (bfraw*)(wsb + 100663296);       // 16 MiB [16384][512]
    bfraw* kvT_raw = (bfraw*)(wsb + 117440512);       // 16 MiB [64][1024][128]
    bfraw* kvT_ex  = (bfraw*)(wsb + 134217728);       // 16 MiB [64][1024][128]
    bfraw* lkT     = (bfraw*)(wsb + 150994944);       //  4 MiB [64][128][256]
    bfraw* WoT     = (bfraw*)(wsb + 155189248);       //  1 MiB [512][1024]

    // 1. prep: LayerNorm + all weight transposes (one dispatch)
    prep_kernel<<<4096 + 1024 + 512 + 64, 256, 0, stream>>>(
        x, ln_w, ln_b, Wh, Wo, Wqk, normb, WhT, WoT, WqkT);
    // 2. merged h+qk GEMM (128x256, 3-slot 2-resident engine): vT+gate+qq/lq/kk/lkT
    gemm_h256<<<1152, 512, 0, stream>>>(
        normb, WhT, WqkT, bh, bqk, gamma, beta, vT, gate, qq, lq, kk, lkT);
    // 3. fused kv + sim (one dispatch; kv blocks first)
    simkv_kernel<<<512 + 192, 256, 0, stream>>>(qq, kk, attn, vT, lkT, kvT_raw);
    // 4. exclusive cumsum over groups (with /G) -> kvT_ex
    cumsum2_kernel<<<(BATCH * QKD * HIDD) / 256, 256, 0, stream>>>(kvT_raw, kvT_ex);
    // 5. gated = gate .* (attn@vv + lq@kv_ex)  (8-wave 3-slot engine)
    quadlin256<<<512, 512, 0, stream>>>(attn, vT, lq, kvT_ex, gate, gated);
    // 6. out = gated @ Wo + bo + x  (16-wave 256x128 engine, 256 blocks)
    gemm_final<<<256, 1024, 0, stream>>>(gated, WoT, bo, x, out);
}